// Round 2
// baseline (1230.400 us; speedup 1.0000x reference)
//
#include <hip/hip_runtime.h>
#include <cstdint>
#include <cstddef>

#define TOK    32768   // B*L
#define BATCH  8
#define SEQ    4096
#define DMODEL 256
#define DINNER 512
#define DSTATE 64
#define NH     16
#define HD     32
#define DPROJ  1168    // 2*DINNER + 2*DSTATE + NH
#define CONVD  640     // DINNER + 2*DSTATE
#define VOCAB  512

// ws layout (floats)
#define RMSF_OFF  0
#define Z_OFF     (RMSF_OFF + TOK)                    // 16.78M
#define XBC_OFF   (Z_OFF + (size_t)TOK*DINNER)        // 20.97M
#define DTS_OFF   (XBC_OFF + (size_t)TOK*CONVD)       // 0.52M
#define ACS_OFF   (DTS_OFF + (size_t)TOK*NH)          // 0.52M
#define CDEC_OFF  (ACS_OFF + (size_t)BATCH*NH*64*64)  // 8K
#define STXF_OFF  (CDEC_OFF + (size_t)BATCH*NH*64)    // 16.78M (st, later xf)
#define WS_FLOATS (STXF_OFF + (size_t)BATCH*64*NH*2048)

// ---------------- diag fallback: report ws_size via absmax ----------------
__global__ void k_diag(float* out, float wsmb) {
    if (blockIdx.x == 0 && threadIdx.x == 0) out[0] = wsmb;
}

// ---------------- K1: per-token rms factor ----------------
__global__ void k_rmsf(const int* __restrict__ ids, const float* __restrict__ embed,
                       float* __restrict__ rmsf) {
    int t = blockIdx.x;
    int lane = threadIdx.x;   // 64 threads
    int id = ids[t];
    float4 v = ((const float4*)(embed + (size_t)id * DMODEL))[lane];
    float ss = v.x*v.x + v.y*v.y + v.z*v.z + v.w*v.w;
    #pragma unroll
    for (int o = 32; o > 0; o >>= 1) ss += __shfl_down(ss, o);
    if (lane == 0) rmsf[t] = rsqrtf(ss * (1.0f / DMODEL) + 1e-6f);
}

// ---------------- K2: in_proj GEMM with fused embed-gather A, conv+silu / softplus epilogue ----------------
__global__ __launch_bounds__(256) void k_inproj(const int* __restrict__ ids, const float* __restrict__ embed,
                                                const float* __restrict__ norm_w, const float* __restrict__ rmsf,
                                                const float* __restrict__ W, const float* __restrict__ cw,
                                                const float* __restrict__ cb, const float* __restrict__ dt_bias,
                                                float* __restrict__ z, float* __restrict__ xbc,
                                                float* __restrict__ dts) {
    __shared__ float As[16][64];
    __shared__ float Bs[16][64];
    __shared__ float T[67][64];
    int tid = threadIdx.x;
    int tx = tid & 15, ty = tid >> 4;
    int m0 = blockIdx.y << 6, n0 = blockIdx.x << 6;
    float acc[4][4] = {};
    int r = tid >> 2, kq = (tid & 3) << 2;
    int m = m0 + r;
    int id = ids[m];
    float rf = rmsf[m];
    for (int k0 = 0; k0 < DMODEL; k0 += 16) {
        float4 va = *(const float4*)(embed + (size_t)id * DMODEL + k0 + kq);
        float4 nw = *(const float4*)(norm_w + k0 + kq);
        va.x *= rf * nw.x; va.y *= rf * nw.y; va.z *= rf * nw.z; va.w *= rf * nw.w;
        As[kq+0][r] = va.x; As[kq+1][r] = va.y; As[kq+2][r] = va.z; As[kq+3][r] = va.w;
        int nr = n0 + r;
        float4 vb;
        if (nr < DPROJ) vb = *(const float4*)(W + (size_t)nr * DMODEL + k0 + kq);
        else { vb.x = 0.f; vb.y = 0.f; vb.z = 0.f; vb.w = 0.f; }
        Bs[kq+0][r] = vb.x; Bs[kq+1][r] = vb.y; Bs[kq+2][r] = vb.z; Bs[kq+3][r] = vb.w;
        __syncthreads();
        #pragma unroll
        for (int kk = 0; kk < 16; kk++) {
            float a[4], b[4];
            #pragma unroll
            for (int i = 0; i < 4; i++) a[i] = As[kk][ty*4 + i];
            #pragma unroll
            for (int j = 0; j < 4; j++) b[j] = Bs[kk][tx*4 + j];
            #pragma unroll
            for (int i = 0; i < 4; i++)
                #pragma unroll
                for (int j = 0; j < 4; j++) acc[i][j] = fmaf(a[i], b[j], acc[i][j]);
        }
        __syncthreads();
    }
    if (n0 < DINNER) {
        // z columns: direct store
        #pragma unroll
        for (int i = 0; i < 4; i++)
            #pragma unroll
            for (int j = 0; j < 4; j++)
                z[(size_t)(m0 + ty*4 + i) * DINNER + n0 + tx*4 + j] = acc[i][j];
    } else if (n0 < DINNER + CONVD) {
        // xBC columns: stage tile + 3-row halo, conv(k=4) + silu
        #pragma unroll
        for (int i = 0; i < 4; i++)
            #pragma unroll
            for (int j = 0; j < 4; j++)
                T[3 + ty*4 + i][tx*4 + j] = acc[i][j];
        bool haveHalo = (m0 & (SEQ - 1)) != 0;
        if (tid < 192) {
            int hr = tid >> 6, n = tid & 63;
            if (haveHalo) {
                int hm = m0 - 3 + hr;
                int hid = ids[hm];
                float hrf = rmsf[hm];
                const float4* er = (const float4*)(embed + (size_t)hid * DMODEL);
                const float4* nr4 = (const float4*)norm_w;
                const float4* wr = (const float4*)(W + (size_t)(n0 + n) * DMODEL);
                float s = 0.f;
                #pragma unroll 8
                for (int k4 = 0; k4 < DMODEL/4; k4++) {
                    float4 e = er[k4], nw = nr4[k4], w = wr[k4];
                    s += e.x*nw.x*w.x + e.y*nw.y*w.y + e.z*nw.z*w.z + e.w*nw.w*w.w;
                }
                T[hr][n] = s * hrf;
            } else {
                T[hr][n] = 0.f;
            }
        }
        __syncthreads();
        int l0 = m0 & (SEQ - 1);
        #pragma unroll
        for (int i = 0; i < 4; i++) {
            int il = ty*4 + i;
            #pragma unroll
            for (int j = 0; j < 4; j++) {
                int n = tx*4 + j;
                int ch = n0 + n - DINNER;
                float s = cb[ch];
                #pragma unroll
                for (int w = 0; w < 4; w++) {
                    if (l0 + il + w >= 3) s = fmaf(T[il + w][n], cw[ch*4 + w], s);
                }
                s = s / (1.f + expf(-s));
                xbc[(size_t)(m0 + il) * CONVD + ch] = s;
            }
        }
    } else {
        // dt columns: softplus(acc + dt_bias)
        #pragma unroll
        for (int i = 0; i < 4; i++) {
            #pragma unroll
            for (int j = 0; j < 4; j++) {
                int n = tx*4 + j;
                if (n < NH) {
                    float v = acc[i][j] + dt_bias[n];
                    v = (v > 20.f) ? v : log1pf(expf(v));
                    dts[(size_t)(m0 + ty*4 + i) * NH + n] = v;
                }
            }
        }
    }
}

// ---------------- K3: generic fp32 GEMM  C[M,N] = A[M,K] @ B[N,K]^T (+ embed-gather residual) ----------------
__global__ __launch_bounds__(256) void k_gemm(const float* __restrict__ A, const float* __restrict__ B,
                                              float* __restrict__ C, int M, int N, int K,
                                              const int* __restrict__ rid, const float* __restrict__ remb) {
    __shared__ float As[16][64];
    __shared__ float Bs[16][64];
    int tid = threadIdx.x;
    int tx = tid & 15, ty = tid >> 4;
    int m0 = blockIdx.y << 6, n0 = blockIdx.x << 6;
    float acc[4][4] = {};
    int r = tid >> 2, kq = (tid & 3) << 2;
    for (int k0 = 0; k0 < K; k0 += 16) {
        float4 va = *(const float4*)(A + (size_t)(m0 + r) * K + k0 + kq);
        As[kq+0][r] = va.x; As[kq+1][r] = va.y; As[kq+2][r] = va.z; As[kq+3][r] = va.w;
        int nr = n0 + r;
        float4 vb;
        if (nr < N) vb = *(const float4*)(B + (size_t)nr * K + k0 + kq);
        else { vb.x = 0.f; vb.y = 0.f; vb.z = 0.f; vb.w = 0.f; }
        Bs[kq+0][r] = vb.x; Bs[kq+1][r] = vb.y; Bs[kq+2][r] = vb.z; Bs[kq+3][r] = vb.w;
        __syncthreads();
        #pragma unroll
        for (int kk = 0; kk < 16; kk++) {
            float a[4], b[4];
            #pragma unroll
            for (int i = 0; i < 4; i++) a[i] = As[kk][ty*4 + i];
            #pragma unroll
            for (int j = 0; j < 4; j++) b[j] = Bs[kk][tx*4 + j];
            #pragma unroll
            for (int i = 0; i < 4; i++)
                #pragma unroll
                for (int j = 0; j < 4; j++) acc[i][j] = fmaf(a[i], b[j], acc[i][j]);
        }
        __syncthreads();
    }
    #pragma unroll
    for (int i = 0; i < 4; i++) {
        int m = m0 + ty*4 + i;
        const float* er = remb ? (remb + (size_t)rid[m] * N) : nullptr;  // only for N==DMODEL
        #pragma unroll
        for (int j = 0; j < 4; j++) {
            int n = n0 + tx*4 + j;
            if (n < N) {
                float v = acc[i][j];
                if (er) v += er[n];
                C[(size_t)m * N + n] = v;
            }
        }
    }
}

// ---------------- K4a: per-(b,chunk): Y_diag + states + cumsums ----------------
__global__ __launch_bounds__(256) void k_chunk(const float* __restrict__ xbc, const float* __restrict__ dts,
                                               const float* __restrict__ A_log,
                                               float* __restrict__ Y, float* __restrict__ states,
                                               float* __restrict__ acs_g, float* __restrict__ cdec) {
    __shared__ float Cs[64][65];   // C at start, reused as W per head
    __shared__ float Bsh[64][65];
    __shared__ float Mm[64][65];
    __shared__ float Xs[64][33];
    __shared__ float acs[64];
    __shared__ float dk[64];
    int tid = threadIdx.x;
    int bc = blockIdx.x;
    int b = bc >> 6, c = bc & 63;
    size_t tbase = (size_t)b * SEQ + (size_t)c * 64;
    for (int i = tid; i < 64*64; i += 256) {
        int q = i >> 6, n = i & 63;
        const float* rowp = xbc + (tbase + q) * CONVD;
        Cs[q][n]  = rowp[DINNER + DSTATE + n];
        Bsh[q][n] = rowp[DINNER + n];
    }
    __syncthreads();
    for (int i = tid; i < 64*64; i += 256) {
        int q = i >> 6, k = i & 63;
        float s = 0.f;
        if (k <= q) {
            #pragma unroll
            for (int n = 0; n < 64; n++) s = fmaf(Cs[q][n], Bsh[k][n], s);
        }
        Mm[q][k] = s;
    }
    __syncthreads();
    for (int h = 0; h < NH; h++) {
        if (tid < 64) {
            float Ah = -expf(A_log[h]);
            float v = dts[(tbase + tid) * NH + h] * Ah;
            #pragma unroll
            for (int off = 1; off < 64; off <<= 1) {
                float o = __shfl_up(v, off);
                if (tid >= off) v += o;
            }
            acs[tid] = v;
            acs_g[(((size_t)(b*NH + h)) * 64 + c) * 64 + tid] = v;
            float alast = __shfl(v, 63);
            dk[tid] = expf(alast - v);
            if (tid == 0) cdec[(b*NH + h) * 64 + c] = expf(alast);
        }
        for (int i = tid; i < 64*32; i += 256) {
            int k = i >> 5, p = i & 31;
            Xs[k][p] = xbc[(tbase + k) * CONVD + h*HD + p] * dts[(tbase + k) * NH + h];
        }
        __syncthreads();
        for (int i = tid; i < 64*64; i += 256) {
            int q = i >> 6, k = i & 63;
            Cs[q][k] = (k <= q) ? Mm[q][k] * expf(acs[q] - acs[k]) : 0.f;
        }
        __syncthreads();
        for (int i = tid; i < 64*32; i += 256) {
            int q = i >> 5, p = i & 31;
            float s = 0.f;
            for (int k = 0; k <= q; k++) s = fmaf(Cs[q][k], Xs[k][p], s);
            Y[((tbase + q) * NH + h) * HD + p] = s;
        }
        for (int i = tid; i < 32*64; i += 256) {
            int p = i >> 6, n = i & 63;
            float s = 0.f;
            #pragma unroll
            for (int k = 0; k < 64; k++) s = fmaf(Bsh[k][n] * dk[k], Xs[k][p], s);
            states[(((size_t)bc) * NH + h) * 2048 + i] = s;
        }
        __syncthreads();
    }
}

// ---------------- K4b: sequential inter-chunk scan ----------------
__global__ __launch_bounds__(256) void k_scan(float* __restrict__ states, const float* __restrict__ cdec) {
    int bh = blockIdx.x;
    int b = bh >> 4, h = bh & 15;
    int tid = threadIdx.x;
    float prev[8];
    #pragma unroll
    for (int j = 0; j < 8; j++) prev[j] = 0.f;
    for (int c = 0; c < 64; c++) {
        float dec = cdec[bh * 64 + c];
        size_t base = ((((size_t)b * 64 + c) * NH) + h) * 2048;
        #pragma unroll
        for (int j = 0; j < 8; j++) {
            size_t idx = base + j*256 + tid;
            float st = states[idx];
            states[idx] = prev[j];
            prev[j] = fmaf(dec, prev[j], st);
        }
    }
}

// ---------------- K4c: Y += exp(acs[q]) * (C[q] . prev[p,:]) + D*x ----------------
__global__ __launch_bounds__(256) void k_yoff(const float* __restrict__ xbc, const float* __restrict__ states,
                                              const float* __restrict__ acs_g, const float* __restrict__ D_skip,
                                              float* __restrict__ Y) {
    __shared__ float Cs[64][65];
    __shared__ float P[32][65];
    __shared__ float expq[64];
    int tid = threadIdx.x;
    int bc = blockIdx.x;
    int b = bc >> 6, c = bc & 63;
    size_t tbase = (size_t)b * SEQ + (size_t)c * 64;
    for (int i = tid; i < 64*64; i += 256) {
        int q = i >> 6, n = i & 63;
        Cs[q][n] = xbc[(tbase + q) * CONVD + DINNER + DSTATE + n];
    }
    for (int h = 0; h < NH; h++) {
        __syncthreads();
        if (tid < 64) expq[tid] = expf(acs_g[(((size_t)(b*NH + h)) * 64 + c) * 64 + tid]);
        size_t sbase = (((size_t)bc) * NH + h) * 2048;
        for (int i = tid; i < 2048; i += 256) P[i >> 6][i & 63] = states[sbase + i];
        __syncthreads();
        float dsk = D_skip[h];
        for (int i = tid; i < 2048; i += 256) {
            int q = i >> 5, p = i & 31;
            float s = 0.f;
            #pragma unroll
            for (int n = 0; n < 64; n++) s = fmaf(Cs[q][n], P[p][n], s);
            size_t yi = ((tbase + q) * NH + h) * HD + p;
            float xval = xbc[(tbase + q) * CONVD + h*HD + p];
            Y[yi] += expq[q] * s + dsk * xval;
        }
    }
}

// ---------------- K5: y = rmsnorm(y * silu(z), gate_norm_w, 1e-5) in place ----------------
__global__ void k_gate(const float* __restrict__ z, const float* __restrict__ gw,
                       float* __restrict__ Y) {
    int t = blockIdx.x;
    int lane = threadIdx.x;  // 64
    const float4* z4 = (const float4*)(z + (size_t)t * DINNER);
    float4* y4 = (float4*)(Y + (size_t)t * DINNER);
    float4 g[2];
    float ss = 0.f;
    #pragma unroll
    for (int r = 0; r < 2; r++) {
        float4 zv = z4[lane*2 + r];
        float4 yv = y4[lane*2 + r];
        float4 gv;
        gv.x = yv.x * (zv.x / (1.f + expf(-zv.x)));
        gv.y = yv.y * (zv.y / (1.f + expf(-zv.y)));
        gv.z = yv.z * (zv.z / (1.f + expf(-zv.z)));
        gv.w = yv.w * (zv.w / (1.f + expf(-zv.w)));
        ss += gv.x*gv.x + gv.y*gv.y + gv.z*gv.z + gv.w*gv.w;
        g[r] = gv;
    }
    #pragma unroll
    for (int o = 32; o > 0; o >>= 1) ss += __shfl_down(ss, o);
    ss = __shfl(ss, 0);
    float rr = rsqrtf(ss * (1.0f / DINNER) + 1e-5f);
    const float4* w4 = (const float4*)gw;
    #pragma unroll
    for (int r = 0; r < 2; r++) {
        float4 wv = w4[lane*2 + r];
        float4 ov;
        ov.x = g[r].x * rr * wv.x; ov.y = g[r].y * rr * wv.y;
        ov.z = g[r].z * rr * wv.z; ov.w = g[r].w * rr * wv.w;
        y4[lane*2 + r] = ov;
    }
}

extern "C" void kernel_launch(void* const* d_in, const int* in_sizes, int n_in,
                              void* d_out, int out_size, void* d_ws, size_t ws_size,
                              hipStream_t stream) {
    const int*   ids        = (const int*)d_in[0];
    const float* embed_w    = (const float*)d_in[1];
    const float* in_proj_w  = (const float*)d_in[2];
    const float* conv_w     = (const float*)d_in[3];
    const float* conv_b     = (const float*)d_in[4];
    const float* A_log      = (const float*)d_in[5];
    const float* D_skip     = (const float*)d_in[6];
    const float* dt_bias    = (const float*)d_in[7];
    const float* gate_w     = (const float*)d_in[8];
    const float* out_proj_w = (const float*)d_in[9];
    const float* norm_w     = (const float*)d_in[10];
    float* out = (float*)d_out;

    if (ws_size < WS_FLOATS * sizeof(float)) {
        // workspace too small — report its size (MB) through the absmax channel
        k_diag<<<1, 64, 0, stream>>>(out, (float)(ws_size >> 20));
        return;
    }

    float* ws   = (float*)d_ws;
    float* rmsf = ws + RMSF_OFF;
    float* z    = ws + Z_OFF;
    float* xbc  = ws + XBC_OFF;
    float* dts  = ws + DTS_OFF;
    float* acs  = ws + ACS_OFF;
    float* cdec = ws + CDEC_OFF;
    float* st   = ws + STXF_OFF;
    float* xf   = ws + STXF_OFF;   // aliases st (st dead after k_yoff)
    float* Y    = out;             // logits GEMM fully overwrites d_out at the end

    k_rmsf<<<TOK, 64, 0, stream>>>(ids, embed_w, rmsf);
    k_inproj<<<dim3((DPROJ + 63) / 64, TOK / 64), 256, 0, stream>>>(
        ids, embed_w, norm_w, rmsf, in_proj_w, conv_w, conv_b, dt_bias, z, xbc, dts);
    k_chunk<<<BATCH * 64, 256, 0, stream>>>(xbc, dts, A_log, Y, st, acs, cdec);
    k_scan<<<BATCH * NH, 256, 0, stream>>>(st, cdec);
    k_yoff<<<BATCH * 64, 256, 0, stream>>>(xbc, st, acs, D_skip, Y);
    k_gate<<<TOK, 64, 0, stream>>>(z, gate_w, Y);
    k_gemm<<<dim3(DMODEL / 64, TOK / 64), 256, 0, stream>>>(Y, out_proj_w, xf, TOK, DMODEL, DINNER, ids, embed_w);
    k_gemm<<<dim3(VOCAB / 64, TOK / 64), 256, 0, stream>>>(xf, embed_w, out, TOK, VOCAB, DMODEL, nullptr, nullptr);
}

// Round 3
// 737.832 us; speedup vs baseline: 1.6676x; 1.6676x over previous
//
#include <hip/hip_runtime.h>
#include <cstdint>
#include <cstddef>

#define TOK    32768   // B*L
#define BATCH  8
#define SEQ    4096
#define DMODEL 256
#define DINNER 512
#define DSTATE 64
#define NH     16
#define HD     32
#define DPROJ  1168
#define NPAD   1280    // in_proj N padded to 10*128
#define CONVD  640
#define VOCAB  512

typedef __attribute__((ext_vector_type(8))) short bf16x8;
typedef __attribute__((ext_vector_type(4))) float f32x4;

__device__ __forceinline__ unsigned short f2bf(float f) {
    unsigned u = __float_as_uint(f);
    u += 0x7fffu + ((u >> 16) & 1u);       // RNE
    return (unsigned short)(u >> 16);
}
__device__ __forceinline__ float bf2f(short s) {
    return __uint_as_float(((unsigned)(unsigned short)s) << 16);
}
__device__ __forceinline__ float sp(float v) { return v > 20.f ? v : log1pf(expf(v)); }

// ---------------- ws layout (floats, all 16B aligned) ----------------
#define U16_OFF   0                                    // TOK*256 bf16 = TOK*128 fl
#define Z16_OFF   (U16_OFF  + (size_t)TOK*128)         // TOK*512 bf16 = TOK*256 fl
#define XBC_OFF   (Z16_OFF  + (size_t)TOK*256)         // TOK*640 fp32
#define DTS_OFF   (XBC_OFF  + (size_t)TOK*640)         // TOK*16
#define ACS_OFF   (DTS_OFF  + (size_t)TOK*16)          // 8*16*64*64
#define CDEC_OFF  (ACS_OFF  + (size_t)BATCH*NH*64*64)  // 8192
#define WP_OFF    (CDEC_OFF + (size_t)BATCH*NH*64)     // 1280*256 bf16 = 163840 fl
#define WO_OFF    (WP_OFF   + 163840)                  // 256*512 bf16 = 65536 fl
#define WE_OFF    (WO_OFF   + 65536)                   // 512*256 bf16 = 65536 fl
#define UNION_OFF (WE_OFF   + 65536)
// union: raw bf16 TOK*640 (10.49M fl) | st fp32 (16.78M fl) | Yb bf16 TOK*512 (8.39M fl) + xf16 TOK*256 (4.19M fl)
#define UNION_FL  ((size_t)BATCH*64*NH*2048)
#define XF_SUB    ((size_t)TOK*256)                    // xf16 at UNION + TOK*256 floats (after Yb)
#define WS_FLOATS (UNION_OFF + UNION_FL)

__global__ void k_diag(float* out, float wsmb) {
    if (blockIdx.x == 0 && threadIdx.x == 0) out[0] = wsmb;
}

// ---------------- weight fp32 -> bf16 (+ zero pad) ----------------
__global__ void k_cvt(const float* __restrict__ s, short* __restrict__ d, int nsrc, int ntot) {
    int i = blockIdx.x * 256 + threadIdx.x;
    if (i < ntot) d[i] = (i < nsrc) ? (short)f2bf(s[i]) : (short)0;
}

// ---------------- embed gather + rmsnorm -> u16 (bf16) ----------------
__global__ void k_embed(const int* __restrict__ ids, const float* __restrict__ embed,
                        const float* __restrict__ norm_w, short* __restrict__ u16) {
    int t = blockIdx.x;
    int lane = threadIdx.x;   // 64
    int id = ids[t];
    float4 v = ((const float4*)(embed + (size_t)id * DMODEL))[lane];
    float ss = v.x*v.x + v.y*v.y + v.z*v.z + v.w*v.w;
    #pragma unroll
    for (int o = 32; o > 0; o >>= 1) ss += __shfl_down(ss, o);
    ss = __shfl(ss, 0);
    float r = rsqrtf(ss * (1.0f / DMODEL) + 1e-6f);
    float4 w = ((const float4*)norm_w)[lane];
    unsigned p0 = (unsigned)f2bf(v.x * r * w.x) | ((unsigned)f2bf(v.y * r * w.y) << 16);
    unsigned p1 = (unsigned)f2bf(v.z * r * w.z) | ((unsigned)f2bf(v.w * r * w.w) << 16);
    ((uint2*)(u16 + (size_t)t * DMODEL))[lane] = make_uint2(p0, p1);
}

// ---------------- bf16 MFMA GEMM: C[M,N] = A[M,K] @ B[N,K]^T, fused epilogues ----------------
// MODE 0: in_proj (N=1280 padded): cols 0-511 -> z16, 512-1151 -> raw bf16, 1152-1167 -> softplus dt
// MODE 1: out_proj (N=256): + embed[ids] residual -> xf16 bf16
// MODE 2: logits  (N=512): fp32 store to out
template<int MODE>
__global__ __launch_bounds__(256) void k_gemm_mfma(
    const short* __restrict__ A, const short* __restrict__ B, int K,
    float* __restrict__ outF, short* __restrict__ z16, short* __restrict__ raw,
    float* __restrict__ dts, const float* __restrict__ dt_bias,
    const int* __restrict__ ids, const float* __restrict__ embed) {
    __shared__ short As[128 * 40];
    __shared__ short Bs[128 * 40];
    int tid = threadIdx.x;
    int m0 = blockIdx.y << 7;
    int n0 = blockIdx.x << 7;
    int wave = tid >> 6, lane = tid & 63;
    int wm = wave >> 1, wn = wave & 1;
    int lr = lane & 15, lg = lane >> 4;
    const f32x4 zer = {0.f, 0.f, 0.f, 0.f};
    f32x4 acc[4][4];
    #pragma unroll
    for (int i = 0; i < 4; i++)
        #pragma unroll
        for (int j = 0; j < 4; j++) acc[i][j] = zer;

    int nK = K >> 5;
    for (int kt = 0; kt < nK; ++kt) {
        int k0 = kt << 5;
        __syncthreads();
        #pragma unroll
        for (int j = 0; j < 2; ++j) {
            int u = tid * 2 + j;          // 0..511
            int row = u >> 2, un = u & 3;
            int4 va = ((const int4*)(A + (size_t)(m0 + row) * K + k0))[un];
            *(int4*)&As[row * 40 + un * 8] = va;
            int4 vb = ((const int4*)(B + (size_t)(n0 + row) * K + k0))[un];
            *(int4*)&Bs[row * 40 + un * 8] = vb;
        }
        __syncthreads();
        bf16x8 af[4], bfr[4];
        #pragma unroll
        for (int mi = 0; mi < 4; mi++)
            af[mi] = *(const bf16x8*)&As[(wm * 64 + mi * 16 + lr) * 40 + lg * 8];
        #pragma unroll
        for (int ni = 0; ni < 4; ni++)
            bfr[ni] = *(const bf16x8*)&Bs[(wn * 64 + ni * 16 + lr) * 40 + lg * 8];
        #pragma unroll
        for (int mi = 0; mi < 4; mi++)
            #pragma unroll
            for (int ni = 0; ni < 4; ni++)
                acc[mi][ni] = __builtin_amdgcn_mfma_f32_16x16x32_bf16(af[mi], bfr[ni], acc[mi][ni], 0, 0, 0);
    }

    // epilogue: row = m0 + wm*64 + mi*16 + lg*4 + r ; col = n0 + wn*64 + ni*16 + lr
    #pragma unroll
    for (int mi = 0; mi < 4; mi++) {
        #pragma unroll
        for (int r = 0; r < 4; r++) {
            int row = m0 + wm * 64 + mi * 16 + lg * 4 + r;
            #pragma unroll
            for (int ni = 0; ni < 4; ni++) {
                int col = n0 + wn * 64 + ni * 16 + lr;
                float v = acc[mi][ni][r];
                if (MODE == 0) {
                    if (n0 < 512) {
                        z16[(size_t)row * DINNER + col] = (short)f2bf(v);
                    } else if (n0 < 1152) {
                        raw[(size_t)row * CONVD + (col - DINNER)] = (short)f2bf(v);
                    } else if (wn == 0 && ni == 0) {   // cols 1152..1167
                        dts[(size_t)row * NH + lr] = sp(v + dt_bias[lr]);
                    }
                } else if (MODE == 1) {
                    float res = embed[(size_t)ids[row] * DMODEL + col];
                    z16[(size_t)row * DMODEL + col] = (short)f2bf(v + res);  // z16 = xf16 here
                } else {
                    outF[(size_t)row * VOCAB + col] = v;
                }
            }
        }
    }
}

// ---------------- causal depthwise conv (k=4) + SiLU, raw bf16 -> xbc fp32 ----------------
__global__ void k_conv(const short* __restrict__ raw, const float* __restrict__ cw,
                       const float* __restrict__ cb, float* __restrict__ xbc) {
    int idx = blockIdx.x * 256 + threadIdx.x;
    if (idx >= TOK * CONVD) return;
    int ch = idx % CONVD;
    int t = idx / CONVD;
    int l = t & (SEQ - 1);
    const short* src = raw + (size_t)t * CONVD + ch;
    float acc = cb[ch];
    #pragma unroll
    for (int w = 0; w < 4; w++) {
        int d = w - 3;
        if (l + d >= 0) acc = fmaf(bf2f(src[(long)d * CONVD]), cw[ch * 4 + w], acc);
    }
    xbc[idx] = acc / (1.f + expf(-acc));
}

// ---------------- K4a: per-(b,chunk): Y_diag + states + cumsums ----------------
__global__ __launch_bounds__(256) void k_chunk(const float* __restrict__ xbc, const float* __restrict__ dts,
                                               const float* __restrict__ A_log,
                                               float* __restrict__ Y, float* __restrict__ states,
                                               float* __restrict__ acs_g, float* __restrict__ cdec) {
    __shared__ float Cs[64][65];
    __shared__ float Bsh[64][65];
    __shared__ float Mm[64][65];
    __shared__ float Xs[64][33];
    __shared__ float acs[64];
    __shared__ float dk[64];
    int tid = threadIdx.x;
    int bc = blockIdx.x;
    int b = bc >> 6, c = bc & 63;
    size_t tbase = (size_t)b * SEQ + (size_t)c * 64;
    for (int i = tid; i < 64 * 64; i += 256) {
        int q = i >> 6, n = i & 63;
        const float* rowp = xbc + (tbase + q) * CONVD;
        Cs[q][n]  = rowp[DINNER + DSTATE + n];
        Bsh[q][n] = rowp[DINNER + n];
    }
    __syncthreads();
    for (int i = tid; i < 64 * 64; i += 256) {
        int q = i >> 6, k = i & 63;
        float s = 0.f;
        if (k <= q) {
            #pragma unroll
            for (int n = 0; n < 64; n++) s = fmaf(Cs[q][n], Bsh[k][n], s);
        }
        Mm[q][k] = s;
    }
    __syncthreads();
    for (int h = 0; h < NH; h++) {
        if (tid < 64) {
            float Ah = -expf(A_log[h]);
            float v = dts[(tbase + tid) * NH + h] * Ah;
            #pragma unroll
            for (int off = 1; off < 64; off <<= 1) {
                float o = __shfl_up(v, off);
                if (tid >= off) v += o;
            }
            acs[tid] = v;
            acs_g[(((size_t)(b * NH + h)) * 64 + c) * 64 + tid] = v;
            float alast = __shfl(v, 63);
            dk[tid] = expf(alast - v);
            if (tid == 0) cdec[(b * NH + h) * 64 + c] = expf(alast);
        }
        for (int i = tid; i < 64 * 32; i += 256) {
            int k = i >> 5, p = i & 31;
            Xs[k][p] = xbc[(tbase + k) * CONVD + h * HD + p] * dts[(tbase + k) * NH + h];
        }
        __syncthreads();
        for (int i = tid; i < 64 * 64; i += 256) {
            int q = i >> 6, k = i & 63;
            Cs[q][k] = (k <= q) ? Mm[q][k] * expf(acs[q] - acs[k]) : 0.f;
        }
        __syncthreads();
        for (int i = tid; i < 64 * 32; i += 256) {
            int q = i >> 5, p = i & 31;
            float s = 0.f;
            for (int k = 0; k <= q; k++) s = fmaf(Cs[q][k], Xs[k][p], s);
            Y[((tbase + q) * NH + h) * HD + p] = s;
        }
        for (int i = tid; i < 32 * 64; i += 256) {
            int p = i >> 6, n = i & 63;
            float s = 0.f;
            #pragma unroll
            for (int k = 0; k < 64; k++) s = fmaf(Bsh[k][n] * dk[k], Xs[k][p], s);
            states[(((size_t)bc) * NH + h) * 2048 + i] = s;
        }
        __syncthreads();
    }
}

// ---------------- K4b: sequential inter-chunk scan ----------------
__global__ __launch_bounds__(256) void k_scan(float* __restrict__ states, const float* __restrict__ cdec) {
    int bh = blockIdx.x;
    int b = bh >> 4, h = bh & 15;
    int tid = threadIdx.x;
    float prev[8];
    #pragma unroll
    for (int j = 0; j < 8; j++) prev[j] = 0.f;
    for (int c = 0; c < 64; c++) {
        float dec = cdec[bh * 64 + c];
        size_t base = ((((size_t)b * 64 + c) * NH) + h) * 2048;
        #pragma unroll
        for (int j = 0; j < 8; j++) {
            size_t idx = base + j * 256 + tid;
            float st = states[idx];
            states[idx] = prev[j];
            prev[j] = fmaf(dec, prev[j], st);
        }
    }
}

// ---------------- K4c: Y += exp(acs[q]) * (C[q] . prev[p,:]) + D*x ----------------
__global__ __launch_bounds__(256) void k_yoff(const float* __restrict__ xbc, const float* __restrict__ states,
                                              const float* __restrict__ acs_g, const float* __restrict__ D_skip,
                                              float* __restrict__ Y) {
    __shared__ float Cs[64][65];
    __shared__ float P[32][65];
    __shared__ float expq[64];
    int tid = threadIdx.x;
    int bc = blockIdx.x;
    int b = bc >> 6, c = bc & 63;
    size_t tbase = (size_t)b * SEQ + (size_t)c * 64;
    for (int i = tid; i < 64 * 64; i += 256) {
        int q = i >> 6, n = i & 63;
        Cs[q][n] = xbc[(tbase + q) * CONVD + DINNER + DSTATE + n];
    }
    for (int h = 0; h < NH; h++) {
        __syncthreads();
        if (tid < 64) expq[tid] = expf(acs_g[(((size_t)(b * NH + h)) * 64 + c) * 64 + tid]);
        size_t sbase = (((size_t)bc) * NH + h) * 2048;
        for (int i = tid; i < 2048; i += 256) P[i >> 6][i & 63] = states[sbase + i];
        __syncthreads();
        float dsk = D_skip[h];
        for (int i = tid; i < 2048; i += 256) {
            int q = i >> 5, p = i & 31;
            float s = 0.f;
            #pragma unroll
            for (int n = 0; n < 64; n++) s = fmaf(Cs[q][n], P[p][n], s);
            size_t yi = ((tbase + q) * NH + h) * HD + p;
            float xval = xbc[(tbase + q) * CONVD + h * HD + p];
            Y[yi] += expq[q] * s + dsk * xval;
        }
    }
}

// ---------------- gate: Yb = bf16( rmsnorm(Y * silu(z16), gw, 1e-5) ) ----------------
__global__ void k_gate(const float* __restrict__ Y, const short* __restrict__ z16,
                       const float* __restrict__ gw, short* __restrict__ Yb) {
    int t = blockIdx.x;
    int lane = threadIdx.x;  // 64
    const float* yr = Y + (size_t)t * DINNER + lane * 8;
    union { int4 v; short s[8]; } zu;
    zu.v = *(const int4*)(z16 + (size_t)t * DINNER + lane * 8);
    float4 y0 = *(const float4*)yr;
    float4 y1 = *(const float4*)(yr + 4);
    float yv[8] = {y0.x, y0.y, y0.z, y0.w, y1.x, y1.y, y1.z, y1.w};
    float g[8];
    float ss = 0.f;
    #pragma unroll
    for (int i = 0; i < 8; i++) {
        float zf = bf2f(zu.s[i]);
        g[i] = yv[i] * zf / (1.f + expf(-zf));
        ss += g[i] * g[i];
    }
    #pragma unroll
    for (int o = 32; o > 0; o >>= 1) ss += __shfl_down(ss, o);
    ss = __shfl(ss, 0);
    float rr = rsqrtf(ss * (1.0f / DINNER) + 1e-5f);
    const float* wr = gw + lane * 8;
    float4 w0 = *(const float4*)wr;
    float4 w1 = *(const float4*)(wr + 4);
    float wv[8] = {w0.x, w0.y, w0.z, w0.w, w1.x, w1.y, w1.z, w1.w};
    union { int4 v; unsigned short s[8]; } ou;
    #pragma unroll
    for (int i = 0; i < 8; i++) ou.s[i] = f2bf(g[i] * rr * wv[i]);
    *(int4*)(Yb + (size_t)t * DINNER + lane * 8) = ou.v;
}

extern "C" void kernel_launch(void* const* d_in, const int* in_sizes, int n_in,
                              void* d_out, int out_size, void* d_ws, size_t ws_size,
                              hipStream_t stream) {
    const int*   ids        = (const int*)d_in[0];
    const float* embed_w    = (const float*)d_in[1];
    const float* in_proj_w  = (const float*)d_in[2];
    const float* conv_w     = (const float*)d_in[3];
    const float* conv_b     = (const float*)d_in[4];
    const float* A_log      = (const float*)d_in[5];
    const float* D_skip     = (const float*)d_in[6];
    const float* dt_bias    = (const float*)d_in[7];
    const float* gate_w     = (const float*)d_in[8];
    const float* out_proj_w = (const float*)d_in[9];
    const float* norm_w     = (const float*)d_in[10];
    float* out = (float*)d_out;

    if (ws_size < WS_FLOATS * sizeof(float)) {
        k_diag<<<1, 64, 0, stream>>>(out, (float)(ws_size >> 20));
        return;
    }

    float* ws   = (float*)d_ws;
    short* u16  = (short*)(ws + U16_OFF);
    short* z16  = (short*)(ws + Z16_OFF);
    float* xbc  = ws + XBC_OFF;
    float* dts  = ws + DTS_OFF;
    float* acs  = ws + ACS_OFF;
    float* cdec = ws + CDEC_OFF;
    short* Wp   = (short*)(ws + WP_OFF);
    short* Wo   = (short*)(ws + WO_OFF);
    short* We   = (short*)(ws + WE_OFF);
    short* raw  = (short*)(ws + UNION_OFF);
    float* st   = ws + UNION_OFF;
    short* Yb   = (short*)(ws + UNION_OFF);
    short* xf16 = (short*)(ws + UNION_OFF + XF_SUB);
    float* Y    = out;

    k_cvt<<<(NPAD * DMODEL + 255) / 256, 256, 0, stream>>>(in_proj_w, Wp, DPROJ * DMODEL, NPAD * DMODEL);
    k_cvt<<<(DMODEL * DINNER + 255) / 256, 256, 0, stream>>>(out_proj_w, Wo, DMODEL * DINNER, DMODEL * DINNER);
    k_cvt<<<(VOCAB * DMODEL + 255) / 256, 256, 0, stream>>>(embed_w, We, VOCAB * DMODEL, VOCAB * DMODEL);
    k_embed<<<TOK, 64, 0, stream>>>(ids, embed_w, norm_w, u16);
    k_gemm_mfma<0><<<dim3(NPAD / 128, TOK / 128), 256, 0, stream>>>(
        u16, Wp, DMODEL, nullptr, z16, raw, dts, dt_bias, nullptr, nullptr);
    k_conv<<<(TOK * CONVD + 255) / 256, 256, 0, stream>>>(raw, conv_w, conv_b, xbc);
    k_chunk<<<BATCH * 64, 256, 0, stream>>>(xbc, dts, A_log, Y, st, acs, cdec);
    k_scan<<<BATCH * NH, 256, 0, stream>>>(st, cdec);
    k_yoff<<<BATCH * 64, 256, 0, stream>>>(xbc, st, acs, D_skip, Y);
    k_gate<<<TOK, 64, 0, stream>>>(Y, z16, gate_w, Yb);
    k_gemm_mfma<1><<<dim3(DMODEL / 128, TOK / 128), 256, 0, stream>>>(
        Yb, Wo, DINNER, nullptr, xf16, nullptr, nullptr, nullptr, ids, embed_w);
    k_gemm_mfma<2><<<dim3(VOCAB / 128, TOK / 128), 256, 0, stream>>>(
        xf16, We, DMODEL, out, nullptr, nullptr, nullptr, nullptr, nullptr, nullptr);
}

// Round 4
// 380.307 us; speedup vs baseline: 3.2353x; 1.9401x over previous
//
#include <hip/hip_runtime.h>
#include <cstdint>
#include <cstddef>

#define TOK    32768   // B*L
#define BATCH  8
#define SEQ    4096
#define DMODEL 256
#define DINNER 512
#define DSTATE 64
#define NH     16
#define HD     32
#define DPROJ  1168
#define NPAD   1280    // in_proj N padded to 10*128
#define CONVD  640
#define VOCAB  512
#define HGRP   4       // heads per chunk/yoff block

typedef __attribute__((ext_vector_type(8))) short bf16x8;
typedef __attribute__((ext_vector_type(4))) float f32x4;

__device__ __forceinline__ unsigned short f2bf(float f) {
    unsigned u = __float_as_uint(f);
    u += 0x7fffu + ((u >> 16) & 1u);       // RNE
    return (unsigned short)(u >> 16);
}
__device__ __forceinline__ float bf2f(short s) {
    return __uint_as_float(((unsigned)(unsigned short)s) << 16);
}
__device__ __forceinline__ float sp(float v) { return v > 20.f ? v : log1pf(expf(v)); }

// ---------------- ws layout (floats, all 16B aligned) ----------------
#define U16_OFF   0                                    // TOK*256 bf16
#define Z16_OFF   (U16_OFF  + (size_t)TOK*128)         // TOK*512 bf16
#define XBC_OFF   (Z16_OFF  + (size_t)TOK*256)         // TOK*640 bf16
#define DTS_OFF   (XBC_OFF  + (size_t)TOK*320)         // TOK*16 fp32
#define ACS_OFF   (DTS_OFF  + (size_t)TOK*16)
#define CDEC_OFF  (ACS_OFF  + (size_t)BATCH*NH*64*64)
#define WP_OFF    (CDEC_OFF + (size_t)BATCH*NH*64)
#define WO_OFF    (WP_OFF   + 163840)
#define WE_OFF    (WO_OFF   + 65536)
#define UNION_OFF (WE_OFF   + 65536)
// union: raw bf16 TOK*640 | st fp32 8*64*16*2048 | Yb bf16 TOK*512 + xf16 bf16 TOK*256
#define UNION_FL  ((size_t)BATCH*64*NH*2048)
#define XF_SUB    ((size_t)TOK*256)
#define WS_FLOATS (UNION_OFF + UNION_FL)

__global__ void k_diag(float* out, float wsmb) {
    if (blockIdx.x == 0 && threadIdx.x == 0) out[0] = wsmb;
}

// ---------------- weight fp32 -> bf16 (+ zero pad) ----------------
__global__ void k_cvt(const float* __restrict__ s, short* __restrict__ d, int nsrc, int ntot) {
    int i = blockIdx.x * 256 + threadIdx.x;
    if (i < ntot) d[i] = (i < nsrc) ? (short)f2bf(s[i]) : (short)0;
}

// ---------------- embed gather + rmsnorm -> u16 (bf16) ----------------
__global__ void k_embed(const int* __restrict__ ids, const float* __restrict__ embed,
                        const float* __restrict__ norm_w, short* __restrict__ u16) {
    int t = blockIdx.x;
    int lane = threadIdx.x;   // 64
    int id = ids[t];
    float4 v = ((const float4*)(embed + (size_t)id * DMODEL))[lane];
    float ss = v.x*v.x + v.y*v.y + v.z*v.z + v.w*v.w;
    #pragma unroll
    for (int o = 32; o > 0; o >>= 1) ss += __shfl_down(ss, o);
    ss = __shfl(ss, 0);
    float r = rsqrtf(ss * (1.0f / DMODEL) + 1e-6f);
    float4 w = ((const float4*)norm_w)[lane];
    unsigned p0 = (unsigned)f2bf(v.x * r * w.x) | ((unsigned)f2bf(v.y * r * w.y) << 16);
    unsigned p1 = (unsigned)f2bf(v.z * r * w.z) | ((unsigned)f2bf(v.w * r * w.w) << 16);
    ((uint2*)(u16 + (size_t)t * DMODEL))[lane] = make_uint2(p0, p1);
}

// ---------------- bf16 MFMA GEMM: C[M,N] = A[M,K] @ B[N,K]^T, fused epilogues ----------------
template<int MODE>
__global__ __launch_bounds__(256) void k_gemm_mfma(
    const short* __restrict__ A, const short* __restrict__ B, int K,
    float* __restrict__ outF, short* __restrict__ z16, short* __restrict__ raw,
    float* __restrict__ dts, const float* __restrict__ dt_bias,
    const int* __restrict__ ids, const float* __restrict__ embed) {
    __shared__ short As[128 * 40];
    __shared__ short Bs[128 * 40];
    int tid = threadIdx.x;
    int m0 = blockIdx.y << 7;
    int n0 = blockIdx.x << 7;
    int wave = tid >> 6, lane = tid & 63;
    int wm = wave >> 1, wn = wave & 1;
    int lr = lane & 15, lg = lane >> 4;
    const f32x4 zer = {0.f, 0.f, 0.f, 0.f};
    f32x4 acc[4][4];
    #pragma unroll
    for (int i = 0; i < 4; i++)
        #pragma unroll
        for (int j = 0; j < 4; j++) acc[i][j] = zer;

    int nK = K >> 5;
    for (int kt = 0; kt < nK; ++kt) {
        int k0 = kt << 5;
        __syncthreads();
        #pragma unroll
        for (int j = 0; j < 2; ++j) {
            int u = tid * 2 + j;
            int row = u >> 2, un = u & 3;
            int4 va = ((const int4*)(A + (size_t)(m0 + row) * K + k0))[un];
            *(int4*)&As[row * 40 + un * 8] = va;
            int4 vb = ((const int4*)(B + (size_t)(n0 + row) * K + k0))[un];
            *(int4*)&Bs[row * 40 + un * 8] = vb;
        }
        __syncthreads();
        bf16x8 af[4], bfr[4];
        #pragma unroll
        for (int mi = 0; mi < 4; mi++)
            af[mi] = *(const bf16x8*)&As[(wm * 64 + mi * 16 + lr) * 40 + lg * 8];
        #pragma unroll
        for (int ni = 0; ni < 4; ni++)
            bfr[ni] = *(const bf16x8*)&Bs[(wn * 64 + ni * 16 + lr) * 40 + lg * 8];
        #pragma unroll
        for (int mi = 0; mi < 4; mi++)
            #pragma unroll
            for (int ni = 0; ni < 4; ni++)
                acc[mi][ni] = __builtin_amdgcn_mfma_f32_16x16x32_bf16(af[mi], bfr[ni], acc[mi][ni], 0, 0, 0);
    }

    #pragma unroll
    for (int mi = 0; mi < 4; mi++) {
        #pragma unroll
        for (int r = 0; r < 4; r++) {
            int row = m0 + wm * 64 + mi * 16 + lg * 4 + r;
            #pragma unroll
            for (int ni = 0; ni < 4; ni++) {
                int col = n0 + wn * 64 + ni * 16 + lr;
                float v = acc[mi][ni][r];
                if (MODE == 0) {
                    if (n0 < 512) {
                        z16[(size_t)row * DINNER + col] = (short)f2bf(v);
                    } else if (n0 < 1152) {
                        raw[(size_t)row * CONVD + (col - DINNER)] = (short)f2bf(v);
                    } else if (wn == 0 && ni == 0) {
                        dts[(size_t)row * NH + lr] = sp(v + dt_bias[lr]);
                    }
                } else if (MODE == 1) {
                    float res = embed[(size_t)ids[row] * DMODEL + col];
                    z16[(size_t)row * DMODEL + col] = (short)f2bf(v + res);  // xf16
                } else {
                    outF[(size_t)row * VOCAB + col] = v;
                }
            }
        }
    }
}

// ---------------- causal depthwise conv (k=4) + SiLU, raw bf16 -> xbc bf16 ----------------
__global__ void k_conv(const short* __restrict__ raw, const float* __restrict__ cw,
                       const float* __restrict__ cb, short* __restrict__ xbc) {
    int idx = blockIdx.x * 256 + threadIdx.x;
    if (idx >= TOK * CONVD) return;
    int ch = idx % CONVD;
    int t = idx / CONVD;
    int l = t & (SEQ - 1);
    const short* src = raw + (size_t)t * CONVD + ch;
    float acc = cb[ch];
    #pragma unroll
    for (int w = 0; w < 4; w++) {
        int d = w - 3;
        if (l + d >= 0) acc = fmaf(bf2f(src[(long)d * CONVD]), cw[ch * 4 + w], acc);
    }
    xbc[idx] = (short)f2bf(acc / (1.f + expf(-acc)));
}

// ---------------- K4a: per-(b,c,headgroup): M via MFMA, Y_diag + states via MFMA ----------------
__global__ __launch_bounds__(256) void k_chunk(const short* __restrict__ xbc, const float* __restrict__ dts,
                                               const float* __restrict__ A_log,
                                               float* __restrict__ Y, float* __restrict__ states,
                                               float* __restrict__ acs_g, float* __restrict__ cdec) {
    __shared__ short CsB[64 * 72];   // C[q][n]
    __shared__ short BsB[64 * 72];   // B[k][n]
    __shared__ short Wsh[64 * 72];   // W[q][k] per head
    __shared__ short XtS[32 * 72];   // Xt[p][k] per head
    __shared__ short BdS[64 * 72];   // Bd[n][k] per head
    __shared__ float acsS[HGRP][64];
    __shared__ float dkS[HGRP][64];
    int tid = threadIdx.x;
    int bid = blockIdx.x;
    int hg = bid & 3;
    int bc = bid >> 2;
    int b = bc >> 6, c = bc & 63;
    int h0 = hg * HGRP;
    size_t tbase = (size_t)b * SEQ + (size_t)c * 64;
    int wave = tid >> 6, lane = tid & 63;
    int lr = lane & 15, lg = lane >> 4;

    for (int i = tid; i < 64 * 64; i += 256) {
        int q = i >> 6, n = i & 63;
        const short* rowp = xbc + (tbase + q) * CONVD + DINNER;
        BsB[q * 72 + n] = rowp[n];
        CsB[q * 72 + n] = rowp[DSTATE + n];
    }
    {   // wave w computes cumsum for head h0+w
        int h = h0 + wave;
        float Ah = -expf(A_log[h]);
        float v = dts[(tbase + lane) * NH + h] * Ah;
        #pragma unroll
        for (int off = 1; off < 64; off <<= 1) {
            float o = __shfl_up(v, off);
            if (lane >= off) v += o;
        }
        acsS[wave][lane] = v;
        acs_g[(((size_t)(b * NH + h)) * 64 + c) * 64 + lane] = v;
        float alast = __shfl(v, 63);
        dkS[wave][lane] = expf(alast - v);
        if (lane == 0) cdec[(b * NH + h) * 64 + c] = expf(alast);
    }
    __syncthreads();

    // M = C . B^T : wave owns rows 16*wave..16*wave+15, 4 col-tiles, kept in regs
    f32x4 macc[4];
    {
        bf16x8 aw0 = *(const bf16x8*)&CsB[(wave * 16 + lr) * 72 + lg * 8];
        bf16x8 aw1 = *(const bf16x8*)&CsB[(wave * 16 + lr) * 72 + 32 + lg * 8];
        #pragma unroll
        for (int ct = 0; ct < 4; ct++) {
            bf16x8 b0 = *(const bf16x8*)&BsB[(ct * 16 + lr) * 72 + lg * 8];
            bf16x8 b1 = *(const bf16x8*)&BsB[(ct * 16 + lr) * 72 + 32 + lg * 8];
            f32x4 z = {0.f, 0.f, 0.f, 0.f};
            z = __builtin_amdgcn_mfma_f32_16x16x32_bf16(aw0, b0, z, 0, 0, 0);
            z = __builtin_amdgcn_mfma_f32_16x16x32_bf16(aw1, b1, z, 0, 0, 0);
            macc[ct] = z;
        }
    }

    for (int hh = 0; hh < HGRP; hh++) {
        int h = h0 + hh;
        // W[q][k] = tril(M) * exp(acs[q]-acs[k]) -> bf16 LDS (wave writes its row strip)
        #pragma unroll
        for (int ct = 0; ct < 4; ct++) {
            int k = ct * 16 + lr;
            #pragma unroll
            for (int r = 0; r < 4; r++) {
                int q = wave * 16 + lg * 4 + r;
                float wv = 0.f;
                if (k <= q) wv = macc[ct][r] * expf(acsS[hh][q] - acsS[hh][k]);
                Wsh[q * 72 + k] = (short)f2bf(wv);
            }
        }
        // Xt[p][k] = x[k][p] * dt[k]
        for (int i = tid; i < 2048; i += 256) {
            int p = i & 31, k = i >> 5;
            float xv = bf2f(xbc[(tbase + k) * CONVD + h * HD + p]);
            XtS[p * 72 + k] = (short)f2bf(xv * dts[(tbase + k) * NH + h]);
        }
        // Bd[n][k] = B[k][n] * dk[k]
        for (int i = tid; i < 4096; i += 256) {
            int n = i & 63, k = i >> 6;
            BdS[n * 72 + k] = (short)f2bf(bf2f(BsB[k * 72 + n]) * dkS[hh][k]);
        }
        __syncthreads();
        // Y_diag = W . X : wave rows 16*wave, 2 col-tiles (p)
        {
            bf16x8 a0 = *(const bf16x8*)&Wsh[(wave * 16 + lr) * 72 + lg * 8];
            bf16x8 a1 = *(const bf16x8*)&Wsh[(wave * 16 + lr) * 72 + 32 + lg * 8];
            #pragma unroll
            for (int pt = 0; pt < 2; pt++) {
                bf16x8 b0 = *(const bf16x8*)&XtS[(pt * 16 + lr) * 72 + lg * 8];
                bf16x8 b1 = *(const bf16x8*)&XtS[(pt * 16 + lr) * 72 + 32 + lg * 8];
                f32x4 z = {0.f, 0.f, 0.f, 0.f};
                z = __builtin_amdgcn_mfma_f32_16x16x32_bf16(a0, b0, z, 0, 0, 0);
                z = __builtin_amdgcn_mfma_f32_16x16x32_bf16(a1, b1, z, 0, 0, 0);
                #pragma unroll
                for (int r = 0; r < 4; r++) {
                    int q = wave * 16 + lg * 4 + r;
                    Y[((tbase + q) * NH + h) * HD + pt * 16 + lr] = z[r];
                }
            }
        }
        // states[p][n] = sum_k Xt[p][k] * Bd[n][k] : wave: p-tile = wave&1, n-tiles 2*(wave>>1)+{0,1}
        {
            int ptile = wave & 1;
            bf16x8 a0 = *(const bf16x8*)&XtS[(ptile * 16 + lr) * 72 + lg * 8];
            bf16x8 a1 = *(const bf16x8*)&XtS[(ptile * 16 + lr) * 72 + 32 + lg * 8];
            #pragma unroll
            for (int j = 0; j < 2; j++) {
                int nt = (wave >> 1) * 2 + j;
                bf16x8 b0 = *(const bf16x8*)&BdS[(nt * 16 + lr) * 72 + lg * 8];
                bf16x8 b1 = *(const bf16x8*)&BdS[(nt * 16 + lr) * 72 + 32 + lg * 8];
                f32x4 z = {0.f, 0.f, 0.f, 0.f};
                z = __builtin_amdgcn_mfma_f32_16x16x32_bf16(a0, b0, z, 0, 0, 0);
                z = __builtin_amdgcn_mfma_f32_16x16x32_bf16(a1, b1, z, 0, 0, 0);
                #pragma unroll
                for (int r = 0; r < 4; r++) {
                    int p = ptile * 16 + lg * 4 + r;
                    states[((size_t)bc * NH + h) * 2048 + p * 64 + nt * 16 + lr] = z[r];
                }
            }
        }
        __syncthreads();
    }
}

// ---------------- K4b: sequential inter-chunk scan ----------------
__global__ __launch_bounds__(256) void k_scan(float* __restrict__ states, const float* __restrict__ cdec) {
    int bid = blockIdx.x;
    int bh = bid >> 1, half = bid & 1;
    int b = bh >> 4, h = bh & 15;
    int tid = threadIdx.x;
    float prev[4] = {0.f, 0.f, 0.f, 0.f};
    for (int c = 0; c < 64; c++) {
        float dec = cdec[bh * 64 + c];
        size_t base = ((((size_t)b * 64 + c) * NH) + h) * 2048 + half * 1024;
        #pragma unroll
        for (int j = 0; j < 4; j++) {
            size_t idx = base + j * 256 + tid;
            float st = states[idx];
            states[idx] = prev[j];
            prev[j] = fmaf(dec, prev[j], st);
        }
    }
}

// ---------------- K4c: Y += exp(acs[q]) * (C . prev^T) + D*x, via MFMA ----------------
__global__ __launch_bounds__(256) void k_yoff(const short* __restrict__ xbc, const float* __restrict__ states,
                                              const float* __restrict__ acs_g, const float* __restrict__ D_skip,
                                              float* __restrict__ Y) {
    __shared__ short CsB[64 * 72];
    __shared__ short Pt[32 * 72];
    int tid = threadIdx.x;
    int bid = blockIdx.x;
    int hg = bid & 3;
    int bc = bid >> 2;
    int b = bc >> 6, c = bc & 63;
    size_t tbase = (size_t)b * SEQ + (size_t)c * 64;
    int wave = tid >> 6, lane = tid & 63;
    int lr = lane & 15, lg = lane >> 4;
    for (int i = tid; i < 64 * 64; i += 256) {
        int q = i >> 6, n = i & 63;
        CsB[q * 72 + n] = xbc[(tbase + q) * CONVD + DINNER + DSTATE + n];
    }
    for (int hh = 0; hh < HGRP; hh++) {
        int h = hg * HGRP + hh;
        size_t sbase = ((size_t)bc * NH + h) * 2048;
        for (int i = tid; i < 2048; i += 256)
            Pt[(i >> 6) * 72 + (i & 63)] = (short)f2bf(states[sbase + i]);
        __syncthreads();
        const float* arow = acs_g + (((size_t)(b * NH + h)) * 64 + c) * 64;
        float eq[4];
        #pragma unroll
        for (int r = 0; r < 4; r++) eq[r] = expf(arow[wave * 16 + lg * 4 + r]);
        float dsk = D_skip[h];
        bf16x8 a0 = *(const bf16x8*)&CsB[(wave * 16 + lr) * 72 + lg * 8];
        bf16x8 a1 = *(const bf16x8*)&CsB[(wave * 16 + lr) * 72 + 32 + lg * 8];
        #pragma unroll
        for (int pt = 0; pt < 2; pt++) {
            bf16x8 b0 = *(const bf16x8*)&Pt[(pt * 16 + lr) * 72 + lg * 8];
            bf16x8 b1 = *(const bf16x8*)&Pt[(pt * 16 + lr) * 72 + 32 + lg * 8];
            f32x4 z = {0.f, 0.f, 0.f, 0.f};
            z = __builtin_amdgcn_mfma_f32_16x16x32_bf16(a0, b0, z, 0, 0, 0);
            z = __builtin_amdgcn_mfma_f32_16x16x32_bf16(a1, b1, z, 0, 0, 0);
            #pragma unroll
            for (int r = 0; r < 4; r++) {
                int q = wave * 16 + lg * 4 + r;
                int p = pt * 16 + lr;
                size_t yi = ((tbase + q) * NH + h) * HD + p;
                float xv = bf2f(xbc[(tbase + q) * CONVD + h * HD + p]);
                Y[yi] += eq[r] * z[r] + dsk * xv;
            }
        }
        __syncthreads();
    }
}

// ---------------- gate: Yb = bf16( rmsnorm(Y * silu(z16), gw, 1e-5) ) ----------------
__global__ void k_gate(const float* __restrict__ Y, const short* __restrict__ z16,
                       const float* __restrict__ gw, short* __restrict__ Yb) {
    int t = blockIdx.x;
    int lane = threadIdx.x;  // 64
    const float* yr = Y + (size_t)t * DINNER + lane * 8;
    union { int4 v; short s[8]; } zu;
    zu.v = *(const int4*)(z16 + (size_t)t * DINNER + lane * 8);
    float4 y0 = *(const float4*)yr;
    float4 y1 = *(const float4*)(yr + 4);
    float yv[8] = {y0.x, y0.y, y0.z, y0.w, y1.x, y1.y, y1.z, y1.w};
    float g[8];
    float ss = 0.f;
    #pragma unroll
    for (int i = 0; i < 8; i++) {
        float zf = bf2f(zu.s[i]);
        g[i] = yv[i] * zf / (1.f + expf(-zf));
        ss += g[i] * g[i];
    }
    #pragma unroll
    for (int o = 32; o > 0; o >>= 1) ss += __shfl_down(ss, o);
    ss = __shfl(ss, 0);
    float rr = rsqrtf(ss * (1.0f / DINNER) + 1e-5f);
    const float* wr = gw + lane * 8;
    float4 w0 = *(const float4*)wr;
    float4 w1 = *(const float4*)(wr + 4);
    float wv[8] = {w0.x, w0.y, w0.z, w0.w, w1.x, w1.y, w1.z, w1.w};
    union { int4 v; unsigned short s[8]; } ou;
    #pragma unroll
    for (int i = 0; i < 8; i++) ou.s[i] = f2bf(g[i] * rr * wv[i]);
    *(int4*)(Yb + (size_t)t * DINNER + lane * 8) = ou.v;
}

extern "C" void kernel_launch(void* const* d_in, const int* in_sizes, int n_in,
                              void* d_out, int out_size, void* d_ws, size_t ws_size,
                              hipStream_t stream) {
    const int*   ids        = (const int*)d_in[0];
    const float* embed_w    = (const float*)d_in[1];
    const float* in_proj_w  = (const float*)d_in[2];
    const float* conv_w     = (const float*)d_in[3];
    const float* conv_b     = (const float*)d_in[4];
    const float* A_log      = (const float*)d_in[5];
    const float* D_skip     = (const float*)d_in[6];
    const float* dt_bias    = (const float*)d_in[7];
    const float* gate_w     = (const float*)d_in[8];
    const float* out_proj_w = (const float*)d_in[9];
    const float* norm_w     = (const float*)d_in[10];
    float* out = (float*)d_out;

    if (ws_size < WS_FLOATS * sizeof(float)) {
        k_diag<<<1, 64, 0, stream>>>(out, (float)(ws_size >> 20));
        return;
    }

    float* ws   = (float*)d_ws;
    short* u16  = (short*)(ws + U16_OFF);
    short* z16  = (short*)(ws + Z16_OFF);
    short* xbc  = (short*)(ws + XBC_OFF);
    float* dts  = ws + DTS_OFF;
    float* acs  = ws + ACS_OFF;
    float* cdec = ws + CDEC_OFF;
    short* Wp   = (short*)(ws + WP_OFF);
    short* Wo   = (short*)(ws + WO_OFF);
    short* We   = (short*)(ws + WE_OFF);
    short* raw  = (short*)(ws + UNION_OFF);
    float* st   = ws + UNION_OFF;
    short* Yb   = (short*)(ws + UNION_OFF);
    short* xf16 = (short*)(ws + UNION_OFF + XF_SUB);
    float* Y    = out;

    k_cvt<<<(NPAD * DMODEL + 255) / 256, 256, 0, stream>>>(in_proj_w, Wp, DPROJ * DMODEL, NPAD * DMODEL);
    k_cvt<<<(DMODEL * DINNER + 255) / 256, 256, 0, stream>>>(out_proj_w, Wo, DMODEL * DINNER, DMODEL * DINNER);
    k_cvt<<<(VOCAB * DMODEL + 255) / 256, 256, 0, stream>>>(embed_w, We, VOCAB * DMODEL, VOCAB * DMODEL);
    k_embed<<<TOK, 64, 0, stream>>>(ids, embed_w, norm_w, u16);
    k_gemm_mfma<0><<<dim3(NPAD / 128, TOK / 128), 256, 0, stream>>>(
        u16, Wp, DMODEL, nullptr, z16, raw, dts, dt_bias, nullptr, nullptr);
    k_conv<<<(TOK * CONVD + 255) / 256, 256, 0, stream>>>(raw, conv_w, conv_b, xbc);
    k_chunk<<<BATCH * 64 * 4, 256, 0, stream>>>(xbc, dts, A_log, Y, st, acs, cdec);
    k_scan<<<BATCH * NH * 2, 256, 0, stream>>>(st, cdec);
    k_yoff<<<BATCH * 64 * 4, 256, 0, stream>>>(xbc, st, acs, D_skip, Y);
    k_gate<<<TOK, 64, 0, stream>>>(Y, z16, gate_w, Yb);
    k_gemm_mfma<1><<<dim3(DMODEL / 128, TOK / 128), 256, 0, stream>>>(
        Yb, Wo, DINNER, nullptr, xf16, nullptr, nullptr, nullptr, ids, embed_w);
    k_gemm_mfma<2><<<dim3(VOCAB / 128, TOK / 128), 256, 0, stream>>>(
        xf16, We, DMODEL, out, nullptr, nullptr, nullptr, nullptr, nullptr, nullptr);
}

// Round 5
// 349.529 us; speedup vs baseline: 3.5202x; 1.0881x over previous
//
#include <hip/hip_runtime.h>
#include <cstdint>
#include <cstddef>

#define TOK    32768   // B*L
#define BATCH  8
#define SEQ    4096
#define DMODEL 256
#define DINNER 512
#define DSTATE 64
#define NH     16
#define HD     32
#define DPROJ  1168
#define NPAD   1280    // in_proj N padded to 10*128
#define CONVD  640
#define VOCAB  512
#define HGRP   4       // heads per chunk/yoff block
#define TS     132     // conv tile LDS stride (shorts)

typedef __attribute__((ext_vector_type(8))) short bf16x8;
typedef __attribute__((ext_vector_type(4))) float f32x4;

__device__ __forceinline__ unsigned short f2bf(float f) {
    unsigned u = __float_as_uint(f);
    u += 0x7fffu + ((u >> 16) & 1u);       // RNE
    return (unsigned short)(u >> 16);
}
__device__ __forceinline__ float bf2f(short s) {
    return __uint_as_float(((unsigned)(unsigned short)s) << 16);
}
__device__ __forceinline__ float sp(float v) { return v > 20.f ? v : log1pf(expf(v)); }

// ---------------- ws layout (floats, all 16B aligned) ----------------
#define U16_OFF   0                                    // TOK*256 bf16
#define Z16_OFF   (U16_OFF  + (size_t)TOK*128)         // TOK*512 bf16
#define XBC_OFF   (Z16_OFF  + (size_t)TOK*256)         // TOK*640 bf16
#define DTS_OFF   (XBC_OFF  + (size_t)TOK*320)         // TOK*16 fp32
#define ACS_OFF   (DTS_OFF  + (size_t)TOK*16)
#define CDEC_OFF  (ACS_OFF  + (size_t)BATCH*NH*64*64)
#define WP_OFF    (CDEC_OFF + (size_t)BATCH*NH*64)
#define WO_OFF    (WP_OFF   + 163840)
#define WE_OFF    (WO_OFF   + 65536)
#define UNION_OFF (WE_OFF   + 65536)
// union: st fp32 8*64*16*2048 | Yb bf16 TOK*512 + xf16 bf16 TOK*256
#define UNION_FL  ((size_t)BATCH*64*NH*2048)
#define XF_SUB    ((size_t)TOK*256)
#define WS_FLOATS (UNION_OFF + UNION_FL)

__global__ void k_diag(float* out, float wsmb) {
    if (blockIdx.x == 0 && threadIdx.x == 0) out[0] = wsmb;
}

// ---------------- weight fp32 -> bf16 (+ zero pad) ----------------
__global__ void k_cvt(const float* __restrict__ s, short* __restrict__ d, int nsrc, int ntot) {
    int i = blockIdx.x * 256 + threadIdx.x;
    if (i < ntot) d[i] = (i < nsrc) ? (short)f2bf(s[i]) : (short)0;
}

// ---------------- embed gather + rmsnorm -> u16 (bf16) ----------------
__global__ void k_embed(const int* __restrict__ ids, const float* __restrict__ embed,
                        const float* __restrict__ norm_w, short* __restrict__ u16) {
    int t = blockIdx.x;
    int lane = threadIdx.x;   // 64
    int id = ids[t];
    float4 v = ((const float4*)(embed + (size_t)id * DMODEL))[lane];
    float ss = v.x*v.x + v.y*v.y + v.z*v.z + v.w*v.w;
    #pragma unroll
    for (int o = 32; o > 0; o >>= 1) ss += __shfl_down(ss, o);
    ss = __shfl(ss, 0);
    float r = rsqrtf(ss * (1.0f / DMODEL) + 1e-6f);
    float4 w = ((const float4*)norm_w)[lane];
    unsigned p0 = (unsigned)f2bf(v.x * r * w.x) | ((unsigned)f2bf(v.y * r * w.y) << 16);
    unsigned p1 = (unsigned)f2bf(v.z * r * w.z) | ((unsigned)f2bf(v.w * r * w.w) << 16);
    ((uint2*)(u16 + (size_t)t * DMODEL))[lane] = make_uint2(p0, p1);
}

// ---------------- bf16 MFMA GEMM: C[M,N] = A[M,K] @ B[N,K]^T, fused epilogues ----------------
// MODE 0: in_proj: cols<512 -> z16 ; 512..1151 -> fused conv+silu -> xbc ; 1152.. -> softplus dt
// MODE 1: out_proj: + embed[ids] residual -> xf16 (via z16 param)
// MODE 2: logits: fp32 -> outF
template<int MODE>
__global__ __launch_bounds__(256) void k_gemm_mfma(
    const short* __restrict__ A, const short* __restrict__ B, int K,
    float* __restrict__ outF, short* __restrict__ z16, short* __restrict__ xbc,
    float* __restrict__ dts, const float* __restrict__ dt_bias,
    const int* __restrict__ ids, const float* __restrict__ embed,
    const float* __restrict__ cw, const float* __restrict__ cb) {
    __shared__ short SM[MODE == 0 ? (131 * TS) : 10240];   // As|Bs union conv Tile
    short* As = SM;
    short* Bs = SM + 5120;
    int tid = threadIdx.x;
    int m0 = blockIdx.y << 7;
    int n0 = blockIdx.x << 7;
    int wave = tid >> 6, lane = tid & 63;
    int wm = wave >> 1, wn = wave & 1;
    int lr = lane & 15, lg = lane >> 4;
    const f32x4 zer = {0.f, 0.f, 0.f, 0.f};
    f32x4 acc[4][4];
    #pragma unroll
    for (int i = 0; i < 4; i++)
        #pragma unroll
        for (int j = 0; j < 4; j++) acc[i][j] = zer;

    int nK = K >> 5;
    for (int kt = 0; kt < nK; ++kt) {
        int k0 = kt << 5;
        __syncthreads();
        #pragma unroll
        for (int j = 0; j < 2; ++j) {
            int u = tid * 2 + j;
            int row = u >> 2, un = u & 3;
            int4 va = ((const int4*)(A + (size_t)(m0 + row) * K + k0))[un];
            *(int4*)&As[row * 40 + un * 8] = va;
            int4 vb = ((const int4*)(B + (size_t)(n0 + row) * K + k0))[un];
            *(int4*)&Bs[row * 40 + un * 8] = vb;
        }
        __syncthreads();
        bf16x8 af[4], bfr[4];
        #pragma unroll
        for (int mi = 0; mi < 4; mi++)
            af[mi] = *(const bf16x8*)&As[(wm * 64 + mi * 16 + lr) * 40 + lg * 8];
        #pragma unroll
        for (int ni = 0; ni < 4; ni++)
            bfr[ni] = *(const bf16x8*)&Bs[(wn * 64 + ni * 16 + lr) * 40 + lg * 8];
        #pragma unroll
        for (int mi = 0; mi < 4; mi++)
            #pragma unroll
            for (int ni = 0; ni < 4; ni++)
                acc[mi][ni] = __builtin_amdgcn_mfma_f32_16x16x32_bf16(af[mi], bfr[ni], acc[mi][ni], 0, 0, 0);
    }

    if (MODE == 0 && n0 >= 512 && n0 < 1152) {
        // ---- fused causal conv(k=4) + SiLU on this 128x128 xBC tile ----
        short* Tile = SM;   // [131][TS]: rows 0-2 = halo (tokens m0-3..m0-1), 3+r = token m0+r
        __syncthreads();    // waves done reading As/Bs of last K-iter
        #pragma unroll
        for (int mi = 0; mi < 4; mi++)
            #pragma unroll
            for (int ni = 0; ni < 4; ni++)
                #pragma unroll
                for (int r = 0; r < 4; r++) {
                    int row = wm * 64 + mi * 16 + lg * 4 + r;
                    int col = wn * 64 + ni * 16 + lr;
                    Tile[(3 + row) * TS + col] = (short)f2bf(acc[mi][ni][r]);
                }
        bool atStart = (m0 & (SEQ - 1)) == 0;
        for (int e = tid; e < 3 * 128; e += 256) {
            int hr = e >> 7, cc = e & 127;
            float s = 0.f;
            if (!atStart) {
                const short* ar = A + (size_t)(m0 - 3 + hr) * K;
                const short* br = B + (size_t)(n0 + cc) * K;
                #pragma unroll 8
                for (int k = 0; k < 256; k++) s = fmaf(bf2f(ar[k]), bf2f(br[k]), s);
            }
            Tile[hr * TS + cc] = (short)f2bf(s);
        }
        __syncthreads();
        int ch_base = n0 - 512;
        #pragma unroll
        for (int mi = 0; mi < 4; mi++)
            #pragma unroll
            for (int ni = 0; ni < 4; ni++)
                #pragma unroll
                for (int r = 0; r < 4; r++) {
                    int row = wm * 64 + mi * 16 + lg * 4 + r;
                    int col = wn * 64 + ni * 16 + lr;
                    int ch = ch_base + col;
                    float s = cb[ch];
                    #pragma unroll
                    for (int w = 0; w < 4; w++)
                        s = fmaf(bf2f(Tile[(row + w) * TS + col]), cw[ch * 4 + w], s);
                    s = s / (1.f + expf(-s));
                    xbc[(size_t)(m0 + row) * CONVD + ch] = (short)f2bf(s);
                }
        return;
    }

    #pragma unroll
    for (int mi = 0; mi < 4; mi++) {
        #pragma unroll
        for (int r = 0; r < 4; r++) {
            int row = m0 + wm * 64 + mi * 16 + lg * 4 + r;
            #pragma unroll
            for (int ni = 0; ni < 4; ni++) {
                int col = n0 + wn * 64 + ni * 16 + lr;
                float v = acc[mi][ni][r];
                if (MODE == 0) {
                    if (n0 < 512) {
                        z16[(size_t)row * DINNER + col] = (short)f2bf(v);
                    } else if (wn == 0 && ni == 0) {   // dt cols 1152..1167
                        dts[(size_t)row * NH + lr] = sp(v + dt_bias[lr]);
                    }
                } else if (MODE == 1) {
                    float res = embed[(size_t)ids[row] * DMODEL + col];
                    z16[(size_t)row * DMODEL + col] = (short)f2bf(v + res);  // xf16
                } else {
                    outF[(size_t)row * VOCAB + col] = v;
                }
            }
        }
    }
}

// ---------------- K4a: per-(b,c,headgroup): M via MFMA, Y_diag + states via MFMA ----------------
__global__ __launch_bounds__(256) void k_chunk(const short* __restrict__ xbc, const float* __restrict__ dts,
                                               const float* __restrict__ A_log,
                                               float* __restrict__ Y, float* __restrict__ states,
                                               float* __restrict__ acs_g, float* __restrict__ cdec) {
    __shared__ short CsB[64 * 72];   // C[q][n]
    __shared__ short BsB[64 * 72];   // B[k][n]
    __shared__ short Wsh[64 * 72];   // W[q][k] per head
    __shared__ short XtS[32 * 72];   // Xt[p][k] per head
    __shared__ short BdS[64 * 72];   // Bd[n][k] per head
    __shared__ float acsS[HGRP][64];
    __shared__ float dkS[HGRP][64];
    int tid = threadIdx.x;
    int bid = blockIdx.x;
    int hg = bid & 3;
    int bc = bid >> 2;
    int b = bc >> 6, c = bc & 63;
    int h0 = hg * HGRP;
    size_t tbase = (size_t)b * SEQ + (size_t)c * 64;
    int wave = tid >> 6, lane = tid & 63;
    int lr = lane & 15, lg = lane >> 4;

    for (int i = tid; i < 64 * 64; i += 256) {
        int q = i >> 6, n = i & 63;
        const short* rowp = xbc + (tbase + q) * CONVD + DINNER;
        BsB[q * 72 + n] = rowp[n];
        CsB[q * 72 + n] = rowp[DSTATE + n];
    }
    {
        int h = h0 + wave;
        float Ah = -expf(A_log[h]);
        float v = dts[(tbase + lane) * NH + h] * Ah;
        #pragma unroll
        for (int off = 1; off < 64; off <<= 1) {
            float o = __shfl_up(v, off);
            if (lane >= off) v += o;
        }
        acsS[wave][lane] = v;
        acs_g[(((size_t)(b * NH + h)) * 64 + c) * 64 + lane] = v;
        float alast = __shfl(v, 63);
        dkS[wave][lane] = expf(alast - v);
        if (lane == 0) cdec[(b * NH + h) * 64 + c] = expf(alast);
    }
    __syncthreads();

    f32x4 macc[4];
    {
        bf16x8 aw0 = *(const bf16x8*)&CsB[(wave * 16 + lr) * 72 + lg * 8];
        bf16x8 aw1 = *(const bf16x8*)&CsB[(wave * 16 + lr) * 72 + 32 + lg * 8];
        #pragma unroll
        for (int ct = 0; ct < 4; ct++) {
            bf16x8 b0 = *(const bf16x8*)&BsB[(ct * 16 + lr) * 72 + lg * 8];
            bf16x8 b1 = *(const bf16x8*)&BsB[(ct * 16 + lr) * 72 + 32 + lg * 8];
            f32x4 z = {0.f, 0.f, 0.f, 0.f};
            z = __builtin_amdgcn_mfma_f32_16x16x32_bf16(aw0, b0, z, 0, 0, 0);
            z = __builtin_amdgcn_mfma_f32_16x16x32_bf16(aw1, b1, z, 0, 0, 0);
            macc[ct] = z;
        }
    }

    for (int hh = 0; hh < HGRP; hh++) {
        int h = h0 + hh;
        #pragma unroll
        for (int ct = 0; ct < 4; ct++) {
            int k = ct * 16 + lr;
            #pragma unroll
            for (int r = 0; r < 4; r++) {
                int q = wave * 16 + lg * 4 + r;
                float wv = 0.f;
                if (k <= q) wv = macc[ct][r] * expf(acsS[hh][q] - acsS[hh][k]);
                Wsh[q * 72 + k] = (short)f2bf(wv);
            }
        }
        for (int i = tid; i < 2048; i += 256) {
            int p = i & 31, k = i >> 5;
            float xv = bf2f(xbc[(tbase + k) * CONVD + h * HD + p]);
            XtS[p * 72 + k] = (short)f2bf(xv * dts[(tbase + k) * NH + h]);
        }
        for (int i = tid; i < 4096; i += 256) {
            int n = i & 63, k = i >> 6;
            BdS[n * 72 + k] = (short)f2bf(bf2f(BsB[k * 72 + n]) * dkS[hh][k]);
        }
        __syncthreads();
        {
            bf16x8 a0 = *(const bf16x8*)&Wsh[(wave * 16 + lr) * 72 + lg * 8];
            bf16x8 a1 = *(const bf16x8*)&Wsh[(wave * 16 + lr) * 72 + 32 + lg * 8];
            #pragma unroll
            for (int pt = 0; pt < 2; pt++) {
                bf16x8 b0 = *(const bf16x8*)&XtS[(pt * 16 + lr) * 72 + lg * 8];
                bf16x8 b1 = *(const bf16x8*)&XtS[(pt * 16 + lr) * 72 + 32 + lg * 8];
                f32x4 z = {0.f, 0.f, 0.f, 0.f};
                z = __builtin_amdgcn_mfma_f32_16x16x32_bf16(a0, b0, z, 0, 0, 0);
                z = __builtin_amdgcn_mfma_f32_16x16x32_bf16(a1, b1, z, 0, 0, 0);
                #pragma unroll
                for (int r = 0; r < 4; r++) {
                    int q = wave * 16 + lg * 4 + r;
                    Y[((tbase + q) * NH + h) * HD + pt * 16 + lr] = z[r];
                }
            }
        }
        {
            int ptile = wave & 1;
            bf16x8 a0 = *(const bf16x8*)&XtS[(ptile * 16 + lr) * 72 + lg * 8];
            bf16x8 a1 = *(const bf16x8*)&XtS[(ptile * 16 + lr) * 72 + 32 + lg * 8];
            #pragma unroll
            for (int j = 0; j < 2; j++) {
                int nt = (wave >> 1) * 2 + j;
                bf16x8 b0 = *(const bf16x8*)&BdS[(nt * 16 + lr) * 72 + lg * 8];
                bf16x8 b1 = *(const bf16x8*)&BdS[(nt * 16 + lr) * 72 + 32 + lg * 8];
                f32x4 z = {0.f, 0.f, 0.f, 0.f};
                z = __builtin_amdgcn_mfma_f32_16x16x32_bf16(a0, b0, z, 0, 0, 0);
                z = __builtin_amdgcn_mfma_f32_16x16x32_bf16(a1, b1, z, 0, 0, 0);
                #pragma unroll
                for (int r = 0; r < 4; r++) {
                    int p = ptile * 16 + lg * 4 + r;
                    states[((size_t)bc * NH + h) * 2048 + p * 64 + nt * 16 + lr] = z[r];
                }
            }
        }
        __syncthreads();
    }
}

// ---------------- K4b: sequential inter-chunk scan (1 elem/thread) ----------------
__global__ __launch_bounds__(256) void k_scan(float* __restrict__ states, const float* __restrict__ cdec) {
    int bid = blockIdx.x;           // BATCH*NH*8
    int bh = bid >> 3, seg = bid & 7;
    int b = bh >> 4, h = bh & 15;
    int off = seg * 256 + threadIdx.x;
    float prev = 0.f;
    for (int c = 0; c < 64; c++) {
        float dec = cdec[bh * 64 + c];
        size_t idx = ((((size_t)b * 64 + c) * NH) + h) * 2048 + off;
        float st = states[idx];
        states[idx] = prev;
        prev = fmaf(dec, prev, st);
    }
}

// ---------------- K4c: Y += exp(acs[q]) * (C . prev^T) + D*x, via MFMA ----------------
__global__ __launch_bounds__(256) void k_yoff(const short* __restrict__ xbc, const float* __restrict__ states,
                                              const float* __restrict__ acs_g, const float* __restrict__ D_skip,
                                              float* __restrict__ Y) {
    __shared__ short CsB[64 * 72];
    __shared__ short Pt[32 * 72];
    int tid = threadIdx.x;
    int bid = blockIdx.x;
    int hg = bid & 3;
    int bc = bid >> 2;
    int b = bc >> 6, c = bc & 63;
    size_t tbase = (size_t)b * SEQ + (size_t)c * 64;
    int wave = tid >> 6, lane = tid & 63;
    int lr = lane & 15, lg = lane >> 4;
    for (int i = tid; i < 64 * 64; i += 256) {
        int q = i >> 6, n = i & 63;
        CsB[q * 72 + n] = xbc[(tbase + q) * CONVD + DINNER + DSTATE + n];
    }
    for (int hh = 0; hh < HGRP; hh++) {
        int h = hg * HGRP + hh;
        size_t sbase = ((size_t)bc * NH + h) * 2048;
        for (int i = tid; i < 2048; i += 256)
            Pt[(i >> 6) * 72 + (i & 63)] = (short)f2bf(states[sbase + i]);
        __syncthreads();
        const float* arow = acs_g + (((size_t)(b * NH + h)) * 64 + c) * 64;
        float eq[4];
        #pragma unroll
        for (int r = 0; r < 4; r++) eq[r] = expf(arow[wave * 16 + lg * 4 + r]);
        float dsk = D_skip[h];
        bf16x8 a0 = *(const bf16x8*)&CsB[(wave * 16 + lr) * 72 + lg * 8];
        bf16x8 a1 = *(const bf16x8*)&CsB[(wave * 16 + lr) * 72 + 32 + lg * 8];
        #pragma unroll
        for (int pt = 0; pt < 2; pt++) {
            bf16x8 b0 = *(const bf16x8*)&Pt[(pt * 16 + lr) * 72 + lg * 8];
            bf16x8 b1 = *(const bf16x8*)&Pt[(pt * 16 + lr) * 72 + 32 + lg * 8];
            f32x4 z = {0.f, 0.f, 0.f, 0.f};
            z = __builtin_amdgcn_mfma_f32_16x16x32_bf16(a0, b0, z, 0, 0, 0);
            z = __builtin_amdgcn_mfma_f32_16x16x32_bf16(a1, b1, z, 0, 0, 0);
            #pragma unroll
            for (int r = 0; r < 4; r++) {
                int q = wave * 16 + lg * 4 + r;
                int p = pt * 16 + lr;
                size_t yi = ((tbase + q) * NH + h) * HD + p;
                float xv = bf2f(xbc[(tbase + q) * CONVD + h * HD + p]);
                Y[yi] += eq[r] * z[r] + dsk * xv;
            }
        }
        __syncthreads();
    }
}

// ---------------- gate: Yb = bf16( rmsnorm(Y * silu(z16), gw, 1e-5) ) ----------------
__global__ void k_gate(const float* __restrict__ Y, const short* __restrict__ z16,
                       const float* __restrict__ gw, short* __restrict__ Yb) {
    int t = blockIdx.x;
    int lane = threadIdx.x;  // 64
    const float* yr = Y + (size_t)t * DINNER + lane * 8;
    union { int4 v; short s[8]; } zu;
    zu.v = *(const int4*)(z16 + (size_t)t * DINNER + lane * 8);
    float4 y0 = *(const float4*)yr;
    float4 y1 = *(const float4*)(yr + 4);
    float yv[8] = {y0.x, y0.y, y0.z, y0.w, y1.x, y1.y, y1.z, y1.w};
    float g[8];
    float ss = 0.f;
    #pragma unroll
    for (int i = 0; i < 8; i++) {
        float zf = bf2f(zu.s[i]);
        g[i] = yv[i] * zf / (1.f + expf(-zf));
        ss += g[i] * g[i];
    }
    #pragma unroll
    for (int o = 32; o > 0; o >>= 1) ss += __shfl_down(ss, o);
    ss = __shfl(ss, 0);
    float rr = rsqrtf(ss * (1.0f / DINNER) + 1e-5f);
    const float* wr = gw + lane * 8;
    float4 w0 = *(const float4*)wr;
    float4 w1 = *(const float4*)(wr + 4);
    float wv[8] = {w0.x, w0.y, w0.z, w0.w, w1.x, w1.y, w1.z, w1.w};
    union { int4 v; unsigned short s[8]; } ou;
    #pragma unroll
    for (int i = 0; i < 8; i++) ou.s[i] = f2bf(g[i] * rr * wv[i]);
    *(int4*)(Yb + (size_t)t * DINNER + lane * 8) = ou.v;
}

extern "C" void kernel_launch(void* const* d_in, const int* in_sizes, int n_in,
                              void* d_out, int out_size, void* d_ws, size_t ws_size,
                              hipStream_t stream) {
    const int*   ids        = (const int*)d_in[0];
    const float* embed_w    = (const float*)d_in[1];
    const float* in_proj_w  = (const float*)d_in[2];
    const float* conv_w     = (const float*)d_in[3];
    const float* conv_b     = (const float*)d_in[4];
    const float* A_log      = (const float*)d_in[5];
    const float* D_skip     = (const float*)d_in[6];
    const float* dt_bias    = (const float*)d_in[7];
    const float* gate_w     = (const float*)d_in[8];
    const float* out_proj_w = (const float*)d_in[9];
    const float* norm_w     = (const float*)d_in[10];
    float* out = (float*)d_out;

    if (ws_size < WS_FLOATS * sizeof(float)) {
        k_diag<<<1, 64, 0, stream>>>(out, (float)(ws_size >> 20));
        return;
    }

    float* ws   = (float*)d_ws;
    short* u16  = (short*)(ws + U16_OFF);
    short* z16  = (short*)(ws + Z16_OFF);
    short* xbc  = (short*)(ws + XBC_OFF);
    float* dts  = ws + DTS_OFF;
    float* acs  = ws + ACS_OFF;
    float* cdec = ws + CDEC_OFF;
    short* Wp   = (short*)(ws + WP_OFF);
    short* Wo   = (short*)(ws + WO_OFF);
    short* We   = (short*)(ws + WE_OFF);
    float* st   = ws + UNION_OFF;
    short* Yb   = (short*)(ws + UNION_OFF);
    short* xf16 = (short*)(ws + UNION_OFF + XF_SUB);
    float* Y    = out;

    k_cvt<<<(NPAD * DMODEL + 255) / 256, 256, 0, stream>>>(in_proj_w, Wp, DPROJ * DMODEL, NPAD * DMODEL);
    k_cvt<<<(DMODEL * DINNER + 255) / 256, 256, 0, stream>>>(out_proj_w, Wo, DMODEL * DINNER, DMODEL * DINNER);
    k_cvt<<<(VOCAB * DMODEL + 255) / 256, 256, 0, stream>>>(embed_w, We, VOCAB * DMODEL, VOCAB * DMODEL);
    k_embed<<<TOK, 64, 0, stream>>>(ids, embed_w, norm_w, u16);
    k_gemm_mfma<0><<<dim3(NPAD / 128, TOK / 128), 256, 0, stream>>>(
        u16, Wp, DMODEL, nullptr, z16, xbc, dts, dt_bias, nullptr, nullptr, conv_w, conv_b);
    k_chunk<<<BATCH * 64 * 4, 256, 0, stream>>>(xbc, dts, A_log, Y, st, acs, cdec);
    k_scan<<<BATCH * NH * 8, 256, 0, stream>>>(st, cdec);
    k_yoff<<<BATCH * 64 * 4, 256, 0, stream>>>(xbc, st, acs, D_skip, Y);
    k_gate<<<TOK, 64, 0, stream>>>(Y, z16, gate_w, Yb);
    k_gemm_mfma<1><<<dim3(DMODEL / 128, TOK / 128), 256, 0, stream>>>(
        Yb, Wo, DINNER, nullptr, xf16, nullptr, nullptr, nullptr, ids, embed_w, nullptr, nullptr);
    k_gemm_mfma<2><<<dim3(VOCAB / 128, TOK / 128), 256, 0, stream>>>(
        xf16, We, DMODEL, out, nullptr, nullptr, nullptr, nullptr, nullptr, nullptr, nullptr, nullptr);
}

// Round 6
// 319.175 us; speedup vs baseline: 3.8549x; 1.0951x over previous
//
#include <hip/hip_runtime.h>
#include <cstdint>
#include <cstddef>

#define TOK    32768   // B*L
#define BATCH  8
#define SEQ    4096
#define DMODEL 256
#define DINNER 512
#define DSTATE 64
#define NH     16
#define HD     32
#define DPROJ  1168
#define NPAD   1280    // in_proj N padded to 10*128
#define CONVD  640
#define VOCAB  512
#define HGRP   4       // heads per chunk/yoff block
#define TS     132     // conv tile LDS stride (shorts)

typedef __attribute__((ext_vector_type(8))) short bf16x8;
typedef __attribute__((ext_vector_type(4))) float f32x4;

__device__ __forceinline__ unsigned short f2bf(float f) {
    unsigned u = __float_as_uint(f);
    u += 0x7fffu + ((u >> 16) & 1u);       // RNE
    return (unsigned short)(u >> 16);
}
__device__ __forceinline__ float bf2f(short s) {
    return __uint_as_float(((unsigned)(unsigned short)s) << 16);
}
__device__ __forceinline__ float sp(float v) { return v > 20.f ? v : log1pf(expf(v)); }

// ---------------- ws layout (floats, all 16B aligned) ----------------
#define U16_OFF   0                                    // TOK*256 bf16
#define Z16_OFF   (U16_OFF  + (size_t)TOK*128)         // TOK*512 bf16
#define XBC_OFF   (Z16_OFF  + (size_t)TOK*256)         // TOK*640 bf16
#define DTS_OFF   (XBC_OFF  + (size_t)TOK*320)         // TOK*16 fp32
#define ACS_OFF   (DTS_OFF  + (size_t)TOK*16)
#define CDEC_OFF  (ACS_OFF  + (size_t)BATCH*NH*64*64)
#define WP_OFF    (CDEC_OFF + (size_t)BATCH*NH*64)
#define WO_OFF    (WP_OFF   + 163840)
#define WE_OFF    (WO_OFF   + 65536)
#define UNION_OFF (WE_OFF   + 65536)
// union: st fp32 8*64*16*2048 | Yb bf16 TOK*512 + xf16 bf16 TOK*256
#define UNION_FL  ((size_t)BATCH*64*NH*2048)
#define XF_SUB    ((size_t)TOK*256)
#define WS_FLOATS (UNION_OFF + UNION_FL)

__global__ void k_diag(float* out, float wsmb) {
    if (blockIdx.x == 0 && threadIdx.x == 0) out[0] = wsmb;
}

// ---------------- weight fp32 -> bf16 (+ zero pad) ----------------
__global__ void k_cvt(const float* __restrict__ s, short* __restrict__ d, int nsrc, int ntot) {
    int i = blockIdx.x * 256 + threadIdx.x;
    if (i < ntot) d[i] = (i < nsrc) ? (short)f2bf(s[i]) : (short)0;
}

// ---------------- embed gather + rmsnorm -> u16 (bf16) ----------------
__global__ void k_embed(const int* __restrict__ ids, const float* __restrict__ embed,
                        const float* __restrict__ norm_w, short* __restrict__ u16) {
    int t = blockIdx.x;
    int lane = threadIdx.x;   // 64
    int id = ids[t];
    float4 v = ((const float4*)(embed + (size_t)id * DMODEL))[lane];
    float ss = v.x*v.x + v.y*v.y + v.z*v.z + v.w*v.w;
    #pragma unroll
    for (int o = 32; o > 0; o >>= 1) ss += __shfl_down(ss, o);
    ss = __shfl(ss, 0);
    float r = rsqrtf(ss * (1.0f / DMODEL) + 1e-6f);
    float4 w = ((const float4*)norm_w)[lane];
    unsigned p0 = (unsigned)f2bf(v.x * r * w.x) | ((unsigned)f2bf(v.y * r * w.y) << 16);
    unsigned p1 = (unsigned)f2bf(v.z * r * w.z) | ((unsigned)f2bf(v.w * r * w.w) << 16);
    ((uint2*)(u16 + (size_t)t * DMODEL))[lane] = make_uint2(p0, p1);
}

// ---------------- bf16 MFMA GEMM: C[M,N] = A[M,K] @ B[N,K]^T, fused epilogues ----------------
// MODE 0: in_proj: cols<512 -> z16 ; 512..1151 -> fused conv+silu -> xbc (halo via MFMA) ; 1152.. -> dt
// MODE 1: out_proj: + embed[ids] residual -> xf16 (via z16 param)
// MODE 2: logits: fp32 -> outF
template<int MODE>
__global__ __launch_bounds__(256) void k_gemm_mfma(
    const short* __restrict__ A, const short* __restrict__ B, int K,
    float* __restrict__ outF, short* __restrict__ z16, short* __restrict__ xbc,
    float* __restrict__ dts, const float* __restrict__ dt_bias,
    const int* __restrict__ ids, const float* __restrict__ embed,
    const float* __restrict__ cw, const float* __restrict__ cb) {
    __shared__ short SM[MODE == 0 ? (131 * TS) : 10240];   // As|Bs union conv Tile
    short* As = SM;
    short* Bs = SM + 5120;
    int tid = threadIdx.x;
    int m0 = blockIdx.y << 7;
    int n0 = blockIdx.x << 7;
    int wave = tid >> 6, lane = tid & 63;
    int wm = wave >> 1, wn = wave & 1;
    int lr = lane & 15, lg = lane >> 4;
    const f32x4 zer = {0.f, 0.f, 0.f, 0.f};
    f32x4 acc[4][4];
    #pragma unroll
    for (int i = 0; i < 4; i++)
        #pragma unroll
        for (int j = 0; j < 4; j++) acc[i][j] = zer;

    const bool isXBC = (MODE == 0) && (n0 >= 512) && (n0 < 1152);
    const bool atStart = (m0 & (SEQ - 1)) == 0;
    f32x4 hacc[4];
    #pragma unroll
    for (int j = 0; j < 4; j++) hacc[j] = zer;

    int nK = K >> 5;
    for (int kt = 0; kt < nK; ++kt) {
        int k0 = kt << 5;
        __syncthreads();
        #pragma unroll
        for (int j = 0; j < 2; ++j) {
            int u = tid * 2 + j;
            int row = u >> 2, un = u & 3;
            int4 va = ((const int4*)(A + (size_t)(m0 + row) * K + k0))[un];
            *(int4*)&As[row * 40 + un * 8] = va;
            int4 vb = ((const int4*)(B + (size_t)(n0 + row) * K + k0))[un];
            *(int4*)&Bs[row * 40 + un * 8] = vb;
        }
        __syncthreads();
        bf16x8 af[4], bfr[4];
        #pragma unroll
        for (int mi = 0; mi < 4; mi++)
            af[mi] = *(const bf16x8*)&As[(wm * 64 + mi * 16 + lr) * 40 + lg * 8];
        #pragma unroll
        for (int ni = 0; ni < 4; ni++)
            bfr[ni] = *(const bf16x8*)&Bs[(wn * 64 + ni * 16 + lr) * 40 + lg * 8];
        #pragma unroll
        for (int mi = 0; mi < 4; mi++)
            #pragma unroll
            for (int ni = 0; ni < 4; ni++)
                acc[mi][ni] = __builtin_amdgcn_mfma_f32_16x16x32_bf16(af[mi], bfr[ni], acc[mi][ni], 0, 0, 0);
        if (isXBC && wm == 0) {
            // halo rows (tokens m0-3..m0-1) via MFMA: A-frag rows lr<3 from global, rest 0
            bf16x8 ha = {0, 0, 0, 0, 0, 0, 0, 0};
            if (!atStart && lr < 3)
                ha = *(const bf16x8*)(A + (size_t)(m0 - 3 + lr) * K + k0 + lg * 8);
            #pragma unroll
            for (int ni = 0; ni < 4; ni++)
                hacc[ni] = __builtin_amdgcn_mfma_f32_16x16x32_bf16(ha, bfr[ni], hacc[ni], 0, 0, 0);
        }
    }

    if (isXBC) {
        // ---- fused causal conv(k=4) + SiLU on this 128x128 xBC tile ----
        short* Tile = SM;   // [131][TS]: rows 0-2 = halo, 3+r = token m0+r
        __syncthreads();    // waves done reading As/Bs of last K-iter
        #pragma unroll
        for (int mi = 0; mi < 4; mi++)
            #pragma unroll
            for (int ni = 0; ni < 4; ni++)
                #pragma unroll
                for (int r = 0; r < 4; r++) {
                    int row = wm * 64 + mi * 16 + lg * 4 + r;
                    int col = wn * 64 + ni * 16 + lr;
                    unsigned short mv = f2bf(acc[mi][ni][r]);
                    unsigned short ov = (unsigned short)__shfl_xor((int)mv, 1);
                    if ((lr & 1) == 0)   // lane with even col writes the pair as 4B
                        *(unsigned*)&Tile[(3 + row) * TS + col] = (unsigned)mv | ((unsigned)ov << 16);
                }
        if (wm == 0 && lg == 0) {
            #pragma unroll
            for (int ni = 0; ni < 4; ni++)
                #pragma unroll
                for (int r = 0; r < 3; r++)
                    Tile[r * TS + wn * 64 + ni * 16 + lr] = (short)f2bf(hacc[ni][r]);
        }
        __syncthreads();
        int ch_base = n0 - 512;
        #pragma unroll
        for (int mi = 0; mi < 4; mi++)
            #pragma unroll
            for (int ni = 0; ni < 4; ni++)
                #pragma unroll
                for (int r = 0; r < 4; r++) {
                    int row = wm * 64 + mi * 16 + lg * 4 + r;
                    int col = wn * 64 + ni * 16 + lr;
                    int ch = ch_base + col;
                    float s = cb[ch];
                    #pragma unroll
                    for (int w = 0; w < 4; w++)
                        s = fmaf(bf2f(Tile[(row + w) * TS + col]), cw[ch * 4 + w], s);
                    s = s / (1.f + expf(-s));
                    xbc[(size_t)(m0 + row) * CONVD + ch] = (short)f2bf(s);
                }
        return;
    }

    #pragma unroll
    for (int mi = 0; mi < 4; mi++) {
        #pragma unroll
        for (int r = 0; r < 4; r++) {
            int row = m0 + wm * 64 + mi * 16 + lg * 4 + r;
            #pragma unroll
            for (int ni = 0; ni < 4; ni++) {
                int col = n0 + wn * 64 + ni * 16 + lr;
                float v = acc[mi][ni][r];
                if (MODE == 0) {
                    if (n0 < 512) {
                        z16[(size_t)row * DINNER + col] = (short)f2bf(v);
                    } else if (wn == 0 && ni == 0) {   // dt cols 1152..1167
                        dts[(size_t)row * NH + lr] = sp(v + dt_bias[lr]);
                    }
                } else if (MODE == 1) {
                    float res = embed[(size_t)ids[row] * DMODEL + col];
                    z16[(size_t)row * DMODEL + col] = (short)f2bf(v + res);  // xf16
                } else {
                    outF[(size_t)row * VOCAB + col] = v;
                }
            }
        }
    }
}

// ---------------- K4a: per-(b,c,headgroup): M via MFMA, Y_diag + states via MFMA ----------------
__global__ __launch_bounds__(256) void k_chunk(const short* __restrict__ xbc, const float* __restrict__ dts,
                                               const float* __restrict__ A_log,
                                               float* __restrict__ Y, float* __restrict__ states,
                                               float* __restrict__ acs_g, float* __restrict__ cdec) {
    __shared__ short CsB[64 * 72];   // C[q][n]
    __shared__ short BsB[64 * 72];   // B[k][n]
    __shared__ short Wsh[64 * 72];   // W[q][k] per head
    __shared__ short XtS[32 * 72];   // Xt[p][k] per head
    __shared__ short BdS[64 * 72];   // Bd[n][k] per head
    __shared__ float acsS[HGRP][64];
    __shared__ float dkS[HGRP][64];
    int tid = threadIdx.x;
    int bid = blockIdx.x;
    int hg = bid & 3;
    int bc = bid >> 2;
    int b = bc >> 6, c = bc & 63;
    int h0 = hg * HGRP;
    size_t tbase = (size_t)b * SEQ + (size_t)c * 64;
    int wave = tid >> 6, lane = tid & 63;
    int lr = lane & 15, lg = lane >> 4;

    for (int i = tid; i < 64 * 64; i += 256) {
        int q = i >> 6, n = i & 63;
        const short* rowp = xbc + (tbase + q) * CONVD + DINNER;
        BsB[q * 72 + n] = rowp[n];
        CsB[q * 72 + n] = rowp[DSTATE + n];
    }
    {
        int h = h0 + wave;
        float Ah = -expf(A_log[h]);
        float v = dts[(tbase + lane) * NH + h] * Ah;
        #pragma unroll
        for (int off = 1; off < 64; off <<= 1) {
            float o = __shfl_up(v, off);
            if (lane >= off) v += o;
        }
        acsS[wave][lane] = v;
        acs_g[(((size_t)(b * NH + h)) * 64 + c) * 64 + lane] = v;
        float alast = __shfl(v, 63);
        dkS[wave][lane] = expf(alast - v);
        if (lane == 0) cdec[(b * NH + h) * 64 + c] = expf(alast);
    }
    __syncthreads();

    f32x4 macc[4];
    {
        bf16x8 aw0 = *(const bf16x8*)&CsB[(wave * 16 + lr) * 72 + lg * 8];
        bf16x8 aw1 = *(const bf16x8*)&CsB[(wave * 16 + lr) * 72 + 32 + lg * 8];
        #pragma unroll
        for (int ct = 0; ct < 4; ct++) {
            bf16x8 b0 = *(const bf16x8*)&BsB[(ct * 16 + lr) * 72 + lg * 8];
            bf16x8 b1 = *(const bf16x8*)&BsB[(ct * 16 + lr) * 72 + 32 + lg * 8];
            f32x4 z = {0.f, 0.f, 0.f, 0.f};
            z = __builtin_amdgcn_mfma_f32_16x16x32_bf16(aw0, b0, z, 0, 0, 0);
            z = __builtin_amdgcn_mfma_f32_16x16x32_bf16(aw1, b1, z, 0, 0, 0);
            macc[ct] = z;
        }
    }

    for (int hh = 0; hh < HGRP; hh++) {
        int h = h0 + hh;
        #pragma unroll
        for (int ct = 0; ct < 4; ct++) {
            int k = ct * 16 + lr;
            #pragma unroll
            for (int r = 0; r < 4; r++) {
                int q = wave * 16 + lg * 4 + r;
                float wv = 0.f;
                if (k <= q) wv = macc[ct][r] * expf(acsS[hh][q] - acsS[hh][k]);
                Wsh[q * 72 + k] = (short)f2bf(wv);
            }
        }
        for (int i = tid; i < 2048; i += 256) {
            int p = i & 31, k = i >> 5;
            float xv = bf2f(xbc[(tbase + k) * CONVD + h * HD + p]);
            XtS[p * 72 + k] = (short)f2bf(xv * dts[(tbase + k) * NH + h]);
        }
        for (int i = tid; i < 4096; i += 256) {
            int n = i & 63, k = i >> 6;
            BdS[n * 72 + k] = (short)f2bf(bf2f(BsB[k * 72 + n]) * dkS[hh][k]);
        }
        __syncthreads();
        {
            bf16x8 a0 = *(const bf16x8*)&Wsh[(wave * 16 + lr) * 72 + lg * 8];
            bf16x8 a1 = *(const bf16x8*)&Wsh[(wave * 16 + lr) * 72 + 32 + lg * 8];
            #pragma unroll
            for (int pt = 0; pt < 2; pt++) {
                bf16x8 b0 = *(const bf16x8*)&XtS[(pt * 16 + lr) * 72 + lg * 8];
                bf16x8 b1 = *(const bf16x8*)&XtS[(pt * 16 + lr) * 72 + 32 + lg * 8];
                f32x4 z = {0.f, 0.f, 0.f, 0.f};
                z = __builtin_amdgcn_mfma_f32_16x16x32_bf16(a0, b0, z, 0, 0, 0);
                z = __builtin_amdgcn_mfma_f32_16x16x32_bf16(a1, b1, z, 0, 0, 0);
                #pragma unroll
                for (int r = 0; r < 4; r++) {
                    int q = wave * 16 + lg * 4 + r;
                    Y[((tbase + q) * NH + h) * HD + pt * 16 + lr] = z[r];
                }
            }
        }
        {
            int ptile = wave & 1;
            bf16x8 a0 = *(const bf16x8*)&XtS[(ptile * 16 + lr) * 72 + lg * 8];
            bf16x8 a1 = *(const bf16x8*)&XtS[(ptile * 16 + lr) * 72 + 32 + lg * 8];
            #pragma unroll
            for (int j = 0; j < 2; j++) {
                int nt = (wave >> 1) * 2 + j;
                bf16x8 b0 = *(const bf16x8*)&BdS[(nt * 16 + lr) * 72 + lg * 8];
                bf16x8 b1 = *(const bf16x8*)&BdS[(nt * 16 + lr) * 72 + 32 + lg * 8];
                f32x4 z = {0.f, 0.f, 0.f, 0.f};
                z = __builtin_amdgcn_mfma_f32_16x16x32_bf16(a0, b0, z, 0, 0, 0);
                z = __builtin_amdgcn_mfma_f32_16x16x32_bf16(a1, b1, z, 0, 0, 0);
                #pragma unroll
                for (int r = 0; r < 4; r++) {
                    int p = ptile * 16 + lg * 4 + r;
                    states[((size_t)bc * NH + h) * 2048 + p * 64 + nt * 16 + lr] = z[r];
                }
            }
        }
        __syncthreads();
    }
}

// ---------------- K4b: sequential inter-chunk scan (1 elem/thread) ----------------
__global__ __launch_bounds__(256) void k_scan(float* __restrict__ states, const float* __restrict__ cdec) {
    int bid = blockIdx.x;           // BATCH*NH*8
    int bh = bid >> 3, seg = bid & 7;
    int b = bh >> 4, h = bh & 15;
    int off = seg * 256 + threadIdx.x;
    float prev = 0.f;
    for (int c = 0; c < 64; c++) {
        float dec = cdec[bh * 64 + c];
        size_t idx = ((((size_t)b * 64 + c) * NH) + h) * 2048 + off;
        float st = states[idx];
        states[idx] = prev;
        prev = fmaf(dec, prev, st);
    }
}

// ---------------- K4c: Y += exp(acs[q]) * (C . prev^T) + D*x, via MFMA ----------------
__global__ __launch_bounds__(256) void k_yoff(const short* __restrict__ xbc, const float* __restrict__ states,
                                              const float* __restrict__ acs_g, const float* __restrict__ D_skip,
                                              float* __restrict__ Y) {
    __shared__ short CsB[64 * 72];
    __shared__ short Pt[32 * 72];
    int tid = threadIdx.x;
    int bid = blockIdx.x;
    int hg = bid & 3;
    int bc = bid >> 2;
    int b = bc >> 6, c = bc & 63;
    size_t tbase = (size_t)b * SEQ + (size_t)c * 64;
    int wave = tid >> 6, lane = tid & 63;
    int lr = lane & 15, lg = lane >> 4;
    for (int i = tid; i < 64 * 64; i += 256) {
        int q = i >> 6, n = i & 63;
        CsB[q * 72 + n] = xbc[(tbase + q) * CONVD + DINNER + DSTATE + n];
    }
    for (int hh = 0; hh < HGRP; hh++) {
        int h = hg * HGRP + hh;
        size_t sbase = ((size_t)bc * NH + h) * 2048;
        for (int i = tid; i < 2048; i += 256)
            Pt[(i >> 6) * 72 + (i & 63)] = (short)f2bf(states[sbase + i]);
        __syncthreads();
        const float* arow = acs_g + (((size_t)(b * NH + h)) * 64 + c) * 64;
        float eq[4];
        #pragma unroll
        for (int r = 0; r < 4; r++) eq[r] = expf(arow[wave * 16 + lg * 4 + r]);
        float dsk = D_skip[h];
        bf16x8 a0 = *(const bf16x8*)&CsB[(wave * 16 + lr) * 72 + lg * 8];
        bf16x8 a1 = *(const bf16x8*)&CsB[(wave * 16 + lr) * 72 + 32 + lg * 8];
        #pragma unroll
        for (int pt = 0; pt < 2; pt++) {
            bf16x8 b0 = *(const bf16x8*)&Pt[(pt * 16 + lr) * 72 + lg * 8];
            bf16x8 b1 = *(const bf16x8*)&Pt[(pt * 16 + lr) * 72 + 32 + lg * 8];
            f32x4 z = {0.f, 0.f, 0.f, 0.f};
            z = __builtin_amdgcn_mfma_f32_16x16x32_bf16(a0, b0, z, 0, 0, 0);
            z = __builtin_amdgcn_mfma_f32_16x16x32_bf16(a1, b1, z, 0, 0, 0);
            #pragma unroll
            for (int r = 0; r < 4; r++) {
                int q = wave * 16 + lg * 4 + r;
                int p = pt * 16 + lr;
                size_t yi = ((tbase + q) * NH + h) * HD + p;
                float xv = bf2f(xbc[(tbase + q) * CONVD + h * HD + p]);
                Y[yi] += eq[r] * z[r] + dsk * xv;
            }
        }
        __syncthreads();
    }
}

// ---------------- gate: Yb = bf16( rmsnorm(Y * silu(z16), gw, 1e-5) ) ----------------
__global__ void k_gate(const float* __restrict__ Y, const short* __restrict__ z16,
                       const float* __restrict__ gw, short* __restrict__ Yb) {
    int t = blockIdx.x;
    int lane = threadIdx.x;  // 64
    const float* yr = Y + (size_t)t * DINNER + lane * 8;
    union { int4 v; short s[8]; } zu;
    zu.v = *(const int4*)(z16 + (size_t)t * DINNER + lane * 8);
    float4 y0 = *(const float4*)yr;
    float4 y1 = *(const float4*)(yr + 4);
    float yv[8] = {y0.x, y0.y, y0.z, y0.w, y1.x, y1.y, y1.z, y1.w};
    float g[8];
    float ss = 0.f;
    #pragma unroll
    for (int i = 0; i < 8; i++) {
        float zf = bf2f(zu.s[i]);
        g[i] = yv[i] * zf / (1.f + expf(-zf));
        ss += g[i] * g[i];
    }
    #pragma unroll
    for (int o = 32; o > 0; o >>= 1) ss += __shfl_down(ss, o);
    ss = __shfl(ss, 0);
    float rr = rsqrtf(ss * (1.0f / DINNER) + 1e-5f);
    const float* wr = gw + lane * 8;
    float4 w0 = *(const float4*)wr;
    float4 w1 = *(const float4*)(wr + 4);
    float wv[8] = {w0.x, w0.y, w0.z, w0.w, w1.x, w1.y, w1.z, w1.w};
    union { int4 v; unsigned short s[8]; } ou;
    #pragma unroll
    for (int i = 0; i < 8; i++) ou.s[i] = f2bf(g[i] * rr * wv[i]);
    *(int4*)(Yb + (size_t)t * DINNER + lane * 8) = ou.v;
}

extern "C" void kernel_launch(void* const* d_in, const int* in_sizes, int n_in,
                              void* d_out, int out_size, void* d_ws, size_t ws_size,
                              hipStream_t stream) {
    const int*   ids        = (const int*)d_in[0];
    const float* embed_w    = (const float*)d_in[1];
    const float* in_proj_w  = (const float*)d_in[2];
    const float* conv_w     = (const float*)d_in[3];
    const float* conv_b     = (const float*)d_in[4];
    const float* A_log      = (const float*)d_in[5];
    const float* D_skip     = (const float*)d_in[6];
    const float* dt_bias    = (const float*)d_in[7];
    const float* gate_w     = (const float*)d_in[8];
    const float* out_proj_w = (const float*)d_in[9];
    const float* norm_w     = (const float*)d_in[10];
    float* out = (float*)d_out;

    if (ws_size < WS_FLOATS * sizeof(float)) {
        k_diag<<<1, 64, 0, stream>>>(out, (float)(ws_size >> 20));
        return;
    }

    float* ws   = (float*)d_ws;
    short* u16  = (short*)(ws + U16_OFF);
    short* z16  = (short*)(ws + Z16_OFF);
    short* xbc  = (short*)(ws + XBC_OFF);
    float* dts  = ws + DTS_OFF;
    float* acs  = ws + ACS_OFF;
    float* cdec = ws + CDEC_OFF;
    short* Wp   = (short*)(ws + WP_OFF);
    short* Wo   = (short*)(ws + WO_OFF);
    short* We   = (short*)(ws + WE_OFF);
    float* st   = ws + UNION_OFF;
    short* Yb   = (short*)(ws + UNION_OFF);
    short* xf16 = (short*)(ws + UNION_OFF + XF_SUB);
    float* Y    = out;

    k_cvt<<<(NPAD * DMODEL + 255) / 256, 256, 0, stream>>>(in_proj_w, Wp, DPROJ * DMODEL, NPAD * DMODEL);
    k_cvt<<<(DMODEL * DINNER + 255) / 256, 256, 0, stream>>>(out_proj_w, Wo, DMODEL * DINNER, DMODEL * DINNER);
    k_cvt<<<(VOCAB * DMODEL + 255) / 256, 256, 0, stream>>>(embed_w, We, VOCAB * DMODEL, VOCAB * DMODEL);
    k_embed<<<TOK, 64, 0, stream>>>(ids, embed_w, norm_w, u16);
    k_gemm_mfma<0><<<dim3(NPAD / 128, TOK / 128), 256, 0, stream>>>(
        u16, Wp, DMODEL, nullptr, z16, xbc, dts, dt_bias, nullptr, nullptr, conv_w, conv_b);
    k_chunk<<<BATCH * 64 * 4, 256, 0, stream>>>(xbc, dts, A_log, Y, st, acs, cdec);
    k_scan<<<BATCH * NH * 8, 256, 0, stream>>>(st, cdec);
    k_yoff<<<BATCH * 64 * 4, 256, 0, stream>>>(xbc, st, acs, D_skip, Y);
    k_gate<<<TOK, 64, 0, stream>>>(Y, z16, gate_w, Yb);
    k_gemm_mfma<1><<<dim3(DMODEL / 128, TOK / 128), 256, 0, stream>>>(
        Yb, Wo, DINNER, nullptr, xf16, nullptr, nullptr, nullptr, ids, embed_w, nullptr, nullptr);
    k_gemm_mfma<2><<<dim3(VOCAB / 128, TOK / 128), 256, 0, stream>>>(
        xf16, We, DMODEL, out, nullptr, nullptr, nullptr, nullptr, nullptr, nullptr, nullptr, nullptr);
}